// Round 12
// baseline (99.177 us; speedup 1.0000x reference)
//
#include <hip/hip_runtime.h>
#include <math.h>

#define NB 64
#define NS 256
#define ND 64
#define NH2 64
#define NH 128
#define WSTRIDE 4224

// d_out layout (floats):
// 0: out_c[64*3]; 192: rx[64]; 256: ry[64]; 320: ex[64]; 384: ey[64];
// 448: out_c_f[64*3]; 640: prob1[64*3]; 832: prob2[64*3]

#define F4E(v_, e_) ((e_)==0?(v_).x:((e_)==1?(v_).y:((e_)==2?(v_).z:(v_).w)))

typedef __attribute__((ext_vector_type(8))) short bf16x8;
typedef __attribute__((ext_vector_type(4))) float f32x4;

__device__ __forceinline__ unsigned short f2bf(float f){
    union { float f; unsigned int u; } v; v.f = f;
    unsigned int r = v.u + 0x7fffu + ((v.u >> 16) & 1u);
    return (unsigned short)(r >> 16);
}
__device__ __forceinline__ float bf2f(unsigned short h){
    union { unsigned int u; float f; } v; v.u = ((unsigned int)h) << 16;
    return v.f;
}
__device__ __forceinline__ void sw2(unsigned short* ph, unsigned short* pl, int idx, float f){
    unsigned short h = f2bf(f);
    ph[idx] = h;
    pl[idx] = f2bf(f - bf2f(h));
}
__device__ __forceinline__ void sw2x2(unsigned short* ph, unsigned short* pl, int idx, float f0, float f1){
    unsigned short h0 = f2bf(f0), h1 = f2bf(f1);
    ushort2 hh; hh.x = h0; hh.y = h1;
    *(ushort2*)(ph + idx) = hh;
    ushort2 ll; ll.x = f2bf(f0 - bf2f(h0)); ll.y = f2bf(f1 - bf2f(h1));
    *(ushort2*)(pl + idx) = ll;
}

#define LD8(P_, row_, kb_) (*(const bf16x8*)((const char*)(P_) + (size_t)(row_)*144 + (kb_)))

// K=64 tile MAC: acc += A[ar..ar+15][0:64] * B[br..br+15][0:64]^T  (hi/lo 3-combo)
__device__ __forceinline__ f32x4 mm64(
    const unsigned short* Ah, const unsigned short* Al,
    const unsigned short* Bh, const unsigned short* Bl,
    int ar, int br, int lrow, int lkb, f32x4 acc)
{
    const int ra = ar + lrow, rb = br + lrow;
    bf16x8 ah0 = LD8(Ah, ra, lkb), ah1 = LD8(Ah, ra, lkb+64);
    bf16x8 al0 = LD8(Al, ra, lkb), al1 = LD8(Al, ra, lkb+64);
    bf16x8 bh0 = LD8(Bh, rb, lkb), bh1 = LD8(Bh, rb, lkb+64);
    bf16x8 bl0 = LD8(Bl, rb, lkb), bl1 = LD8(Bl, rb, lkb+64);
    acc = __builtin_amdgcn_mfma_f32_16x16x32_bf16(ah0, bh0, acc, 0,0,0);
    acc = __builtin_amdgcn_mfma_f32_16x16x32_bf16(ah1, bh1, acc, 0,0,0);
    acc = __builtin_amdgcn_mfma_f32_16x16x32_bf16(ah0, bl0, acc, 0,0,0);
    acc = __builtin_amdgcn_mfma_f32_16x16x32_bf16(ah1, bl1, acc, 0,0,0);
    acc = __builtin_amdgcn_mfma_f32_16x16x32_bf16(al0, bh0, acc, 0,0,0);
    acc = __builtin_amdgcn_mfma_f32_16x16x32_bf16(al1, bh1, acc, 0,0,0);
    return acc;
}

// =================== K1: MFMA bf16-hi/lo fused MLP, 512 threads / 8 waves ===================
__global__ __launch_bounds__(512) void k1_fused(
    const float* __restrict__ x, const float* __restrict__ y,
    const float* __restrict__ w11_1, const float* __restrict__ b11_1,
    const float* __restrict__ w11_2, const float* __restrict__ b11_2,
    const float* __restrict__ w12_1, const float* __restrict__ b12_1,
    const float* __restrict__ w12_2, const float* __restrict__ b12_2,
    float* __restrict__ out_x, float* __restrict__ out_y,
    float* __restrict__ mean_part)
{
    const int b = blockIdx.x >> 2, tile = blockIdx.x & 3;
    const int t = threadIdx.x;
    const int lane = t & 63, wv = t >> 6;          // wv 0..7
    const int lrow = lane & 15;
    const int lkb  = (lane >> 4) * 16;
    const int row0g = b*NS + tile*64;

    __shared__ unsigned short XYh[9216], XYl[9216];   // 128 rows
    __shared__ unsigned short W1h[4608], W1l[4608];   // 64 rows
    __shared__ unsigned short W2h[4608], W2l[4608];
    __shared__ unsigned short Hh [9216], Hl [9216];
    __shared__ unsigned short Oh [9216], Ol [9216];
    __shared__ float msum[8*68];

    // ---- P0: stage XY + W1^T + W2^T ----
    #pragma unroll
    for (int u=0;u<4;u++){
        int id = t + 512*u;                 // 2048 float4
        int r = id>>4, c0 = (id&15)*4;
        const float* src = (r < 64) ? (x + ((size_t)(row0g + r))*ND)
                                    : (y + ((size_t)(row0g + r - 64))*ND);
        float4 v = *(const float4*)(src + c0);
        sw2x2(XYh, XYl, r*72 + c0,   v.x, v.y);
        sw2x2(XYh, XYl, r*72 + c0+2, v.z, v.w);
    }
    {
        int rp = t>>4, c0 = (t&15)*4;       // 512 row-pair jobs
        float4 a0 = *(const float4*)(w11_1 + (size_t)(2*rp  )*64 + c0);
        float4 a1 = *(const float4*)(w11_1 + (size_t)(2*rp+1)*64 + c0);
        float4 b0 = *(const float4*)(w11_2 + (size_t)(2*rp  )*64 + c0);
        float4 b1 = *(const float4*)(w11_2 + (size_t)(2*rp+1)*64 + c0);
        #pragma unroll
        for (int i2=0;i2<4;i2++){
            sw2x2(W1h, W1l, (c0+i2)*72 + 2*rp, F4E(a0,i2), F4E(a1,i2));
            sw2x2(W2h, W2l, (c0+i2)*72 + 2*rp, F4E(b0,i2), F4E(b1,i2));
        }
    }
    __syncthreads();

    // ---- P1: G1  H = relu(XY @ W1 + b1)  (128x64) : wave w -> rows 16w ----
    {
        const int ar = 16*wv;
        #pragma unroll
        for (int jt=0; jt<4; jt++){
            float bb = b11_1[jt*16 + lrow];
            f32x4 acc = {bb,bb,bb,bb};
            acc = mm64(XYh, XYl, W1h, W1l, ar, jt*16, lrow, lkb, acc);
            #pragma unroll
            for (int e=0;e<4;e++){
                int row = ar + (lane>>4)*4 + e;
                int col = jt*16 + lrow;
                sw2(Hh, Hl, row*72 + col, fmaxf(acc[e], 0.f));
            }
        }
    }
    __syncthreads();

    // ---- P2: stage w12_1^T half0 -> XY region; G2  O = H @ W2 + b2 ----
    #pragma unroll
    for (int u=0;u<2;u++){
        int id = t + 512*u;                 // 1024 row-pair jobs
        int krp = id>>5, c0 = (id&31)*4;
        float4 v0 = *(const float4*)(w12_1 + (size_t)(2*krp  )*NH + c0);
        float4 v1 = *(const float4*)(w12_1 + (size_t)(2*krp+1)*NH + c0);
        #pragma unroll
        for (int i2=0;i2<4;i2++)
            sw2x2(XYh, XYl, (c0+i2)*72 + 2*krp, F4E(v0,i2), F4E(v1,i2));
    }
    {
        const int ar = 16*wv;
        #pragma unroll
        for (int jt=0; jt<4; jt++){
            float bb = b11_2[jt*16 + lrow];
            f32x4 acc = {bb,bb,bb,bb};
            acc = mm64(Hh, Hl, W2h, W2l, ar, jt*16, lrow, lkb, acc);
            #pragma unroll
            for (int e=0;e<4;e++){
                int row = ar + (lane>>4)*4 + e;
                int col = jt*16 + lrow;
                float v = acc[e];
                sw2(Oh, Ol, row*72 + col, v);
                float* dst = (row < 64) ? out_x : out_y;
                dst[((size_t)(row0g + (row & 63)))*NH2 + col] = v;
            }
        }
    }
    __syncthreads();

    // ---- P3: G3 pass0: wave w -> (row-tile rt=w&3, col-tiles 4*(w>>2)+q) ----
    const int rt = wv & 3, cq = wv >> 2;
    f32x4 acc3[4];
    #pragma unroll
    for (int q=0; q<4; q++){
        float bb = b12_1[(4*cq+q)*16 + lrow];
        f32x4 v = {bb,bb,bb,bb};
        acc3[q] = v;
    }
    #pragma unroll
    for (int q=0; q<4; q++)
        acc3[q] = mm64(Oh, Ol, XYh, XYl, 16*rt, 16*(4*cq+q), lrow, lkb, acc3[q]);
    __syncthreads();

    // ---- P4: stage w12_1^T half1 -> XY; w12_2^T halves -> W2(h0)/W1(h1) ----
    #pragma unroll
    for (int u=0;u<2;u++){
        int id = t + 512*u;
        int krp = id>>5, c0 = (id&31)*4;
        float4 v0 = *(const float4*)(w12_1 + (size_t)(64+2*krp  )*NH + c0);
        float4 v1 = *(const float4*)(w12_1 + (size_t)(64+2*krp+1)*NH + c0);
        #pragma unroll
        for (int i2=0;i2<4;i2++)
            sw2x2(XYh, XYl, (c0+i2)*72 + 2*krp, F4E(v0,i2), F4E(v1,i2));
    }
    {
        int krp = t>>4, c0 = (t&15)*4;      // 512 row-pair jobs
        float4 h0a = *(const float4*)(w12_2 + (size_t)(2*krp  )*NH2 + c0);
        float4 h0b = *(const float4*)(w12_2 + (size_t)(2*krp+1)*NH2 + c0);
        float4 h1a = *(const float4*)(w12_2 + (size_t)(64+2*krp  )*NH2 + c0);
        float4 h1b = *(const float4*)(w12_2 + (size_t)(64+2*krp+1)*NH2 + c0);
        #pragma unroll
        for (int i2=0;i2<4;i2++){
            sw2x2(W2h, W2l, (c0+i2)*72 + 2*krp, F4E(h0a,i2), F4E(h0b,i2));
            sw2x2(W1h, W1l, (c0+i2)*72 + 2*krp, F4E(h1a,i2), F4E(h1b,i2));
        }
    }
    __syncthreads();

    // ---- P5: G3 pass1 + epi -> H1 into H region ----
    #pragma unroll
    for (int q=0; q<4; q++)
        acc3[q] = mm64(Oh, Ol, XYh, XYl, 64 + 16*rt, 16*(4*cq+q), lrow, lkb, acc3[q]);
    #pragma unroll
    for (int q=0; q<4; q++){
        #pragma unroll
        for (int e=0;e<4;e++){
            int row = 16*rt + (lane>>4)*4 + e;        // sample 0..63
            int col = 16*(4*cq+q) + lrow;             // 0..127
            float v = fmaxf(acc3[q][e], 0.f);
            int idx = (col < 64) ? (row*72 + col) : ((64+row)*72 + (col-64));
            sw2(Hh, Hl, idx, v);
        }
    }
    __syncthreads();

    // ---- P6: G4: wave w -> (rt, cols (2*cq+q)*16) ----
    {
        f32x4 acc2[2];
        #pragma unroll
        for (int q=0; q<2; q++){
            const int jc = 2*cq + q;
            float bb = b12_2[jc*16 + lrow];
            f32x4 v = {bb,bb,bb,bb};
            acc2[q] = v;
            acc2[q] = mm64(Hh, Hl, W2h, W2l, 16*rt,      16*jc, lrow, lkb, acc2[q]);
            acc2[q] = mm64(Hh, Hl, W1h, W1l, 64 + 16*rt, 16*jc, lrow, lkb, acc2[q]);
        }
        #pragma unroll
        for (int q=0; q<2; q++){
            const int jc = 2*cq + q;
            float s = fmaxf(acc2[q][0],0.f) + fmaxf(acc2[q][1],0.f)
                    + fmaxf(acc2[q][2],0.f) + fmaxf(acc2[q][3],0.f);
            s += __shfl_down(s, 32);
            s += __shfl_down(s, 16);
            if (lane < 16) msum[wv*68 + jc*16 + lane] = s;
        }
    }
    __syncthreads();
    if (t < 64){
        const int w0 = (t>>5)*4;    // cols 0-31 -> waves 0-3 (cq=0); cols 32-63 -> waves 4-7
        float ss = msum[(w0+0)*68 + t] + msum[(w0+1)*68 + t]
                 + msum[(w0+2)*68 + t] + msum[(w0+3)*68 + t];
        mean_part[((size_t)(b*4+tile))*64 + t] = ss;
    }
}

// =================== K2AB: center-first MFMA gram + Neumann/Horner solve ===================
__global__ __launch_bounds__(256) void k2ab(
    const float* __restrict__ fx, const float* __restrict__ fy,
    const float* __restrict__ x, const float* __restrict__ y,
    float* __restrict__ wbuf, int* __restrict__ cnt)
{
    const int bs = blockIdx.x;
    const int side = bs & 1, b = bs >> 1;
    const float* feat = side ? fy : fx;
    const float* targ = side ? x : y;
    float* wb = wbuf + (size_t)bs*WSTRIDE;
    const int t = threadIdx.x;
    const int lane = t & 63, wv = t >> 6;
    const int lrow = lane & 15;
    const int lkb  = (lane >> 4) * 16;
    const float inv256 = 1.0f/256.0f;

    if (bs == 0 && t == 0) *cnt = 0;     // reset kRG completion counter

    __shared__ float Wf[64*68];                 // Ac -> final W
    __shared__ float Rf[64*68];                 // Rc -> R''
    __shared__ unsigned short Zh[4608], Zl[4608], Th[4608], Tl[4608];
    __shared__ unsigned short Eh[4608], El[4608];
    __shared__ unsigned short Wth[2][4608], Wtl[2][4608];
    __shared__ float cspA[16*68], cspB[16*68];
    __shared__ float szs[64], sts[64];
    __shared__ float sc[8], red4[4];

    // ---- Phase A: raw col sums of Z,T and sum T^2 ----
    {
        float szp0=0.f,szp1=0.f,szp2=0.f,szp3=0.f;
        float stp0=0.f,stp1=0.f,stp2=0.f,stp3=0.f;
        float tsq=0.f;
        for (int c=0;c<4;c++){
            #pragma unroll
            for (int u=0;u<4;u++){
                int id = t + 256*u;
                int r = id>>4, c0 = (id&15)*4;
                float4 v = *(const float4*)(feat + ((size_t)(b*NS + c*64 + r))*NH2 + c0);
                float4 w = *(const float4*)(targ + ((size_t)(b*NS + c*64 + r))*ND + c0);
                szp0+=v.x; szp1+=v.y; szp2+=v.z; szp3+=v.w;
                stp0+=w.x; stp1+=w.y; stp2+=w.z; stp3+=w.w;
                tsq += w.x*w.x + w.y*w.y + w.z*w.z + w.w*w.w;
            }
        }
        const int g2 = t>>4, c0 = (t&15)*4;
        cspA[g2*68 + c0+0] = szp0; cspA[g2*68 + c0+1] = szp1;
        cspA[g2*68 + c0+2] = szp2; cspA[g2*68 + c0+3] = szp3;
        cspB[g2*68 + c0+0] = stp0; cspB[g2*68 + c0+1] = stp1;
        cspB[g2*68 + c0+2] = stp2; cspB[g2*68 + c0+3] = stp3;
        float tq = tsq;
        #pragma unroll
        for (int off=32; off; off>>=1) tq += __shfl_down(tq, off);
        if (lane==0) red4[wv] = tq;
    }
    __syncthreads();
    if (t < 64){
        float sa=0.f, sb=0.f;
        #pragma unroll
        for (int g2=0; g2<16; g2++){ sa += cspA[g2*68+t]; sb += cspB[g2*68+t]; }
        szs[t] = sa; sts[t] = sb;
        float s2 = sa*sa;
        #pragma unroll
        for (int off=32; off; off>>=1) s2 += __shfl_down(s2, off);
        if (t==0) sc[2] = s2;                  // sum of col-sum squares
    }
    if (t==0) sc[1] = red4[0]+red4[1]+red4[2]+red4[3];   // tn2
    __syncthreads();

    // ---- Phase B: gram of CENTERED Z, Rc = Zc^T T ----
    f32x4 accA[4], accR[4];
    #pragma unroll
    for (int jt=0;jt<4;jt++){
        f32x4 z = {0.f,0.f,0.f,0.f};
        accA[jt]=z; accR[jt]=z;
    }
    for (int c=0;c<4;c++){
        if (c) __syncthreads();
        #pragma unroll
        for (int u=0;u<4;u++){
            int id = t + 256*u;
            int r = id>>4, c0 = (id&15)*4;
            float4 v = *(const float4*)(feat + ((size_t)(b*NS + c*64 + r))*NH2 + c0);
            float4 w = *(const float4*)(targ + ((size_t)(b*NS + c*64 + r))*ND + c0);
            v.x -= szs[c0+0]*inv256; v.y -= szs[c0+1]*inv256;
            v.z -= szs[c0+2]*inv256; v.w -= szs[c0+3]*inv256;
            sw2(Zh,Zl,(c0+0)*72+r, v.x); sw2(Zh,Zl,(c0+1)*72+r, v.y);
            sw2(Zh,Zl,(c0+2)*72+r, v.z); sw2(Zh,Zl,(c0+3)*72+r, v.w);
            sw2(Th,Tl,(c0+0)*72+r, w.x); sw2(Th,Tl,(c0+1)*72+r, w.y);
            sw2(Th,Tl,(c0+2)*72+r, w.z); sw2(Th,Tl,(c0+3)*72+r, w.w);
        }
        __syncthreads();
        #pragma unroll
        for (int jt=0;jt<4;jt++){
            accA[jt] = mm64(Zh,Zl,Zh,Zl, 16*wv, 16*jt, lrow, lkb, accA[jt]);
            accR[jt] = mm64(Zh,Zl,Th,Tl, 16*wv, 16*jt, lrow, lkb, accR[jt]);
        }
    }
    {
        const int gi0 = 16*wv + (lane>>4)*4;
        #pragma unroll
        for (int jt=0;jt<4;jt++){
            #pragma unroll
            for (int e=0;e<4;e++){
                Wf[(gi0+e)*68 + 16*jt + lrow] = accA[jt][e];   // Ac
                Rf[(gi0+e)*68 + 16*jt + lrow] = accR[jt][e];   // Rc
            }
        }
    }
    __syncthreads();
    if (t<64){
        float dg = Wf[t*68+t];
        #pragma unroll
        for (int off=32; off; off>>=1) dg += __shfl_down(dg, off);
        if (t==0){
            float zn2 = dg + sc[2]*inv256;
            sc[0] = 1.0f/sqrtf(zn2);
            sc[1] = 1.0f/sqrtf(sc[1]);
        }
    }
    __syncthreads();
    const float zinv = sc[0], tinv = sc[1];
    const float z2 = zinv*zinv, zt = zinv*tinv;
    const float i23 = 2.0f/3.0f, i13 = 1.0f/3.0f;
    const int i = t>>2, qd = t&3;
    {
        #pragma unroll
        for (int q=0;q<4;q++){
            const int j = qd*16 + q*4;
            float4 a4 = *(const float4*)(Wf + i*68 + j);
            float e0 = i23*z2*a4.x - ((i==j  ) ? i13 : 0.f);
            float e1 = i23*z2*a4.y - ((i==j+1) ? i13 : 0.f);
            float e2 = i23*z2*a4.z - ((i==j+2) ? i13 : 0.f);
            float e3 = i23*z2*a4.w - ((i==j+3) ? i13 : 0.f);
            sw2x2(Eh, El, i*72 + j,   e0, e1);
            sw2x2(Eh, El, i*72 + j+2, e2, e3);
            float4 rv = *(float4*)(Rf + i*68 + j);
            float r0 = i23*zt*rv.x;
            float r1 = i23*zt*rv.y;
            float r2 = i23*zt*rv.z;
            float r3 = i23*zt*rv.w;
            *(float4*)(Rf + i*68 + j) = make_float4(r0,r1,r2,r3);
            sw2(Wth[0], Wtl[0], (j  )*72 + i, r0);
            sw2(Wth[0], Wtl[0], (j+1)*72 + i, r1);
            sw2(Wth[0], Wtl[0], (j+2)*72 + i, r2);
            sw2(Wth[0], Wtl[0], (j+3)*72 + i, r3);
        }
    }
    __syncthreads();

    int cur = 0;
    for (int n=0; n<12; n++){
        f32x4 acc[4];
        #pragma unroll
        for (int jt=0; jt<4; jt++){
            f32x4 zz = {0.f,0.f,0.f,0.f};
            acc[jt] = mm64(Eh, El, Wth[cur], Wtl[cur], 16*wv, jt*16, lrow, lkb, zz);
        }
        const int gi0 = 16*wv + (lane>>4)*4;
        #pragma unroll
        for (int jt=0; jt<4; jt++){
            const int gj = jt*16 + lrow;
            float w0 = Rf[(gi0  )*68 + gj] - acc[jt][0];
            float w1 = Rf[(gi0+1)*68 + gj] - acc[jt][1];
            float w2 = Rf[(gi0+2)*68 + gj] - acc[jt][2];
            float w3 = Rf[(gi0+3)*68 + gj] - acc[jt][3];
            sw2x2(Wth[cur^1], Wtl[cur^1], gj*72 + gi0,   w0, w1);
            sw2x2(Wth[cur^1], Wtl[cur^1], gj*72 + gi0+2, w2, w3);
            if (n == 11){
                Wf[(gi0  )*68 + gj] = w0;  wb[(gi0  )*64 + gj] = w0;
                Wf[(gi0+1)*68 + gj] = w1;  wb[(gi0+1)*64 + gj] = w1;
                Wf[(gi0+2)*68 + gj] = w2;  wb[(gi0+2)*64 + gj] = w2;
                Wf[(gi0+3)*68 + gj] = w3;  wb[(gi0+3)*64 + gj] = w3;
            }
        }
        cur ^= 1;
        __syncthreads();
    }

    if (t < 64){
        float s = 0.f;
        for (int i2=0; i2<64; i2++) s += szs[i2]*Wf[i2*68 + t];
        wb[4096+t] = (tinv*sts[t] - zinv*s) * inv256;
    }
    if (t==0){ wb[4160] = zinv; wb[4161] = tinv; }
}

// =================== KRG: fused residual + Renyi Gram + (last block) K4 ===================
__global__ __launch_bounds__(256) void kRG(
    const float* __restrict__ fx, const float* __restrict__ fy,
    const float* __restrict__ x, const float* __restrict__ y,
    const float* __restrict__ wbuf,
    float* __restrict__ part3, float* __restrict__ dout,
    const float* __restrict__ mean_part,
    const float* __restrict__ wc1, const float* __restrict__ bc1,
    const float* __restrict__ bn_gamma, const float* __restrict__ bn_beta,
    const float* __restrict__ w2, const float* __restrict__ b2,
    const float* __restrict__ wc2, const float* __restrict__ bc2,
    int* __restrict__ cnt)
{
    const int blk = blockIdx.x;
    const int jh = blk & 1;
    const int b = (blk >> 1) & (NB-1);
    const int side = (blk >> 1) >> 6;
    const float* feat = side ? fy : fx;
    const float* targ = side ? x : y;
    const float* bmat = side ? y : x;
    const float* wb = wbuf + (size_t)(b*2+side)*WSTRIDE;
    const int t = threadIdx.x;
    const int lane = t & 63, wv = t >> 6;
    const int lrow = lane & 15, lkb = (lane>>4)*16;

    __shared__ unsigned short resA[256*72];
    __shared__ unsigned short tgB [256*72];
    __shared__ unsigned short Zh[2*4608], Zl[2*4608];
    __shared__ unsigned short Wth[4608], Wtl[4608];
    __shared__ float c0s[64];
    __shared__ float nAs[256], nBs[256];
    __shared__ float red[4][3];
    __shared__ float lred[4];
    __shared__ int s_last;

    #pragma unroll
    for (int u=0;u<4;u++){
        int id = t + 256*u;
        int k = id>>4, c0 = (id&15)*4;
        float4 v = *(const float4*)(wb + (size_t)k*64 + c0);
        sw2(Wth, Wtl, (c0+0)*72 + k, v.x);
        sw2(Wth, Wtl, (c0+1)*72 + k, v.y);
        sw2(Wth, Wtl, (c0+2)*72 + k, v.z);
        sw2(Wth, Wtl, (c0+3)*72 + k, v.w);
    }
    if (t<64) c0s[t] = wb[4096+t];
    const float zinv = wb[4160], tinv = wb[4161];
    #pragma unroll
    for (int u=0;u<16;u++){
        int id = t + 256*u;
        int r = id>>4, c0 = (id&15)*4;
        float4 v = *(const float4*)(bmat + ((size_t)(b*NS+r))*ND + c0);
        ushort4 h;
        h.x=f2bf(v.x); h.y=f2bf(v.y); h.z=f2bf(v.z); h.w=f2bf(v.w);
        *(ushort4*)(tgB + r*72 + c0) = h;
    }
    #pragma unroll
    for (int u=0;u<4;u++){
        int id = t + 256*u;
        int r = id>>4, c0 = (id&15)*4;
        float4 v = *(const float4*)(feat + ((size_t)(b*NS + r))*NH2 + c0);
        sw2x2(Zh, Zl, r*72+c0,   v.x, v.y);
        sw2x2(Zh, Zl, r*72+c0+2, v.z, v.w);
    }
    __syncthreads();

    float lacc = 0.f;
    for (int c=0; c<4; c++){
        if (c < 3){
            unsigned short* zh = Zh + ((c+1)&1)*4608;
            unsigned short* zl = Zl + ((c+1)&1)*4608;
            #pragma unroll
            for (int u=0;u<4;u++){
                int id = t + 256*u;
                int r = id>>4, c0 = (id&15)*4;
                float4 v = *(const float4*)(feat + ((size_t)(b*NS + (c+1)*64 + r))*NH2 + c0);
                sw2x2(zh, zl, r*72+c0,   v.x, v.y);
                sw2x2(zh, zl, r*72+c0+2, v.z, v.w);
            }
        }
        const unsigned short* zh = Zh + (c&1)*4608;
        const unsigned short* zl = Zl + (c&1)*4608;
        f32x4 acc[4];
        #pragma unroll
        for (int jt=0; jt<4; jt++){
            f32x4 zz = {0.f,0.f,0.f,0.f};
            acc[jt] = mm64(zh, zl, Wth, Wtl, 16*wv, jt*16, lrow, lkb, zz);
        }
        const int r0 = 16*wv + (lane>>4)*4;
        #pragma unroll
        for (int jt=0; jt<4; jt++){
            const int gj = jt*16 + lrow;
            const float cc = c0s[gj];
            #pragma unroll
            for (int e=0;e<4;e++){
                const int grow = c*64 + r0 + e;
                float q = targ[((size_t)(b*NS+grow))*ND + gj];
                float rr = tinv*q - zinv*acc[jt][e] - cc;
                lacc += rr*rr;
                resA[grow*72 + gj] = f2bf(rr);
            }
        }
        __syncthreads();
    }

    {
        float l = lacc;
        #pragma unroll
        for (int off=32; off; off>>=1) l += __shfl_down(l, off);
        if (lane==0) lred[wv] = l;
    }
    {
        float sa=0.f, sb=0.f;
        #pragma unroll
        for (int j8=0;j8<8;j8++){
            bf16x8 va = *(const bf16x8*)((const char*)resA + (size_t)t*144 + j8*16);
            bf16x8 vb = *(const bf16x8*)((const char*)tgB  + (size_t)t*144 + j8*16);
            #pragma unroll
            for (int e2=0;e2<8;e2++){
                float fa = bf2f((unsigned short)va[e2]);
                float fb = bf2f((unsigned short)vb[e2]);
                sa += fa*fa; sb += fb*fb;
            }
        }
        nAs[t] = sa; nBs[t] = sb;
    }
    __syncthreads();
    if (t==0 && jh==0)
        dout[(side?256:192)+b] = lred[0]+lred[1]+lred[2]+lred[3];

    const char* pA = (const char*)resA;
    const char* pB = (const char*)tgB;
    const f32x4 zero4 = {0.f, 0.f, 0.f, 0.f};
    const float CEXP = -2.8853900817779268f;

    float Sa=0.f, Sb=0.f, Sab=0.f;
    #pragma unroll
    for (int it=0; it<4; it++){
        const int i0 = wv*64 + it*16;
        const int arow = i0 + lrow;
        bf16x8 aA0 = *(const bf16x8*)(pA + arow*144 + lkb);
        bf16x8 aA1 = *(const bf16x8*)(pA + arow*144 + lkb + 64);
        bf16x8 aB0 = *(const bf16x8*)(pB + arow*144 + lkb);
        bf16x8 aB1 = *(const bf16x8*)(pB + arow*144 + lkb + 64);
        float nAi[4], nBi[4];
        #pragma unroll
        for (int e=0;e<4;e++){
            int gi = i0 + (lane>>4)*4 + e;
            nAi[e] = nAs[gi]; nBi[e] = nBs[gi];
        }
        #pragma unroll
        for (int jt=0; jt<8; jt++){
            const int j0 = jh*128 + jt*16;
            const int brow = j0 + lrow;
            bf16x8 bA0 = *(const bf16x8*)(pA + brow*144 + lkb);
            bf16x8 bA1 = *(const bf16x8*)(pA + brow*144 + lkb + 64);
            bf16x8 bB0 = *(const bf16x8*)(pB + brow*144 + lkb);
            bf16x8 bB1 = *(const bf16x8*)(pB + brow*144 + lkb + 64);
            f32x4 cA = __builtin_amdgcn_mfma_f32_16x16x32_bf16(aA0, bA0, zero4, 0, 0, 0);
            cA = __builtin_amdgcn_mfma_f32_16x16x32_bf16(aA1, bA1, cA, 0, 0, 0);
            f32x4 cB = __builtin_amdgcn_mfma_f32_16x16x32_bf16(aB0, bB0, zero4, 0, 0, 0);
            cB = __builtin_amdgcn_mfma_f32_16x16x32_bf16(aB1, bB1, cB, 0, 0, 0);
            const int gj = j0 + lrow;
            const float nAj = nAs[gj], nBj = nBs[gj];
            #pragma unroll
            for (int e=0;e<4;e++){
                const int gi = i0 + (lane>>4)*4 + e;
                const float dda = (gi==gj) ? 0.f : (nAi[e] + nAj - 2.f*cA[e]);
                const float ddb = (gi==gj) ? 0.f : (nBi[e] + nBj - 2.f*cB[e]);
                const float ka2 = exp2f(CEXP*dda);
                const float kb2 = exp2f(CEXP*ddb);
                Sa += ka2; Sb += kb2; Sab += ka2*kb2;
            }
        }
    }
    #pragma unroll
    for (int off=32; off; off>>=1){
        Sa += __shfl_down(Sa,off); Sb += __shfl_down(Sb,off); Sab += __shfl_down(Sab,off);
    }
    if (lane==0){ red[wv][0]=Sa; red[wv][1]=Sb; red[wv][2]=Sab; }
    __syncthreads();
    if (t==0){
        float* o = part3 + (size_t)blk*3;
        o[0] = red[0][0]+red[1][0]+red[2][0]+red[3][0];
        o[1] = red[0][1]+red[1][1]+red[2][1]+red[3][1];
        o[2] = red[0][2]+red[1][2]+red[2][2]+red[3][2];
    }

    // ---- last-block runs K4 (device-scope atomic completion) ----
    __threadfence();
    if (t == 0){
        int prev = atomicAdd(cnt, 1);
        s_last = (prev == NB*2*2 - 1);
    }
    __syncthreads();
    if (!s_last) return;
    __threadfence();

    // K4 body, 256 threads (t<64 = batch index), shared reuse of red-free LDS
    __shared__ float ic[64][5];
    __shared__ float mu[5], iv[5];
    if (t < 64){
        float o0 = bc1[0], o1 = bc1[1], o2 = bc1[2];
        for (int c=0;c<64;c++){
            float mv = mean_part[(t*4+0)*64+c] + mean_part[(t*4+1)*64+c]
                     + mean_part[(t*4+2)*64+c] + mean_part[(t*4+3)*64+c];
            mv *= (1.0f/256.0f);
            o0 += mv*wc1[c*3+0]; o1 += mv*wc1[c*3+1]; o2 += mv*wc1[c*3+2];
        }
        dout[t*3+0]=o0; dout[t*3+1]=o1; dout[t*3+2]=o2;
        {
            float m = fmaxf(o0,fmaxf(o1,o2));
            float e0=__expf(o0-m), e1=__expf(o1-m), e2=__expf(o2-m);
            float inv = 1.f/(e0+e1+e2);
            dout[640+t*3+0]=e0*inv; dout[640+t*3+1]=e1*inv; dout[640+t*3+2]=e2*inv;
        }
        float exy[2];
        #pragma unroll
        for (int sd=0; sd<2; sd++){
            const float* pp = part3 + (size_t)((sd*NB + t)*2)*3;
            float Sa2 = pp[0]+pp[3];
            float Sb2 = pp[1]+pp[4];
            float Sab2= pp[2]+pp[5];
            float Hx  = 16.f - log2f(Sa2);
            float Hy  = 16.f - log2f(Sb2);
            float Hxy = 16.f - log2f(Sab2);
            float mi = (Hx + Hy - Hxy) / fmaxf(Hx, Hy);
            dout[(sd?384:320)+t] = mi;
            exy[sd] = mi;
        }
        ic[t][0]=o0; ic[t][1]=o1; ic[t][2]=o2; ic[t][3]=exy[0]; ic[t][4]=exy[1];
    }
    __syncthreads();
    if (t<5){
        float m=0.f;
        for (int bb2=0;bb2<64;bb2++) m += ic[bb2][t];
        m *= (1.f/64.f);
        float v=0.f;
        for (int bb2=0;bb2<64;bb2++){ float d=ic[bb2][t]-m; v+=d*d; }
        v *= (1.f/64.f);
        mu[t]=m; iv[t]=1.f/sqrtf(v+1e-5f);
    }
    __syncthreads();
    if (t < 64){
        float vn[5];
        #pragma unroll
        for (int c=0;c<5;c++) vn[c] = (ic[t][c]-mu[c])*iv[c]*bn_gamma[c]+bn_beta[c];
        float q0=bc2[0], q1=bc2[1], q2=bc2[2];
        for (int j=0;j<64;j++){
            float hh = b2[j];
            #pragma unroll
            for (int c=0;c<5;c++) hh += vn[c]*w2[c*64+j];
            hh = fmaxf(hh,0.f);
            q0 += hh*wc2[j*3+0]; q1 += hh*wc2[j*3+1]; q2 += hh*wc2[j*3+2];
        }
        dout[448+t*3+0]=q0; dout[448+t*3+1]=q1; dout[448+t*3+2]=q2;
        float m = fmaxf(q0,fmaxf(q1,q2));
        float e0=__expf(q0-m), e1=__expf(q1-m), e2=__expf(q2-m);
        float inv=1.f/(e0+e1+e2);
        dout[832+t*3+0]=e0*inv; dout[832+t*3+1]=e1*inv; dout[832+t*3+2]=e2*inv;
    }
}

extern "C" void kernel_launch(void* const* d_in, const int* in_sizes, int n_in,
                              void* d_out, int out_size, void* d_ws, size_t ws_size,
                              hipStream_t stream)
{
    const float* x     = (const float*)d_in[0];
    const float* y     = (const float*)d_in[1];
    const float* w11_1 = (const float*)d_in[2];
    const float* b11_1 = (const float*)d_in[3];
    const float* w11_2 = (const float*)d_in[4];
    const float* b11_2 = (const float*)d_in[5];
    const float* w12_1 = (const float*)d_in[6];
    const float* b12_1 = (const float*)d_in[7];
    const float* w12_2 = (const float*)d_in[8];
    const float* b12_2 = (const float*)d_in[9];
    const float* wc1   = (const float*)d_in[10];
    const float* bc1   = (const float*)d_in[11];
    const float* bn_g  = (const float*)d_in[12];
    const float* bn_b  = (const float*)d_in[13];
    const float* w2    = (const float*)d_in[14];
    const float* b2    = (const float*)d_in[15];
    const float* wc2   = (const float*)d_in[16];
    const float* bc2   = (const float*)d_in[17];

    float* ws   = (float*)d_ws;
    float* dout = (float*)d_out;
    float* out_x = ws;                           // 1,048,576 floats
    float* out_y = ws + 1048576;
    float* mean_part = ws + 2097152;             // 16384
    float* part3 = mean_part + 16384;            // 768 (alloc 3840)
    float* wbuf  = part3 + 3840;                 // 128*4224 = 540672
    int*   cnt   = (int*)(wbuf + 128*WSTRIDE);   // 1 int

    hipLaunchKernelGGL(k1_fused, dim3(NB*4), dim3(512), 0, stream,
        x,y,w11_1,b11_1,w11_2,b11_2,w12_1,b12_1,w12_2,b12_2,
        out_x,out_y,mean_part);
    hipLaunchKernelGGL(k2ab, dim3(2*NB), dim3(256), 0, stream,
        out_x,out_y,x,y,wbuf,cnt);
    hipLaunchKernelGGL(kRG, dim3(NB*2*2), dim3(256), 0, stream,
        out_x,out_y,x,y,wbuf,part3,dout,
        mean_part,wc1,bc1,bn_g,bn_b,w2,b2,wc2,bc2,cnt);
}

// Round 13
// 77.171 us; speedup vs baseline: 1.2852x; 1.2852x over previous
//
#include <hip/hip_runtime.h>
#include <math.h>

#define NB 64
#define NS 256
#define ND 64
#define NH2 64
#define NH 128
#define WSTRIDE 4224

// d_out layout (floats):
// 0: out_c[64*3]; 192: rx[64]; 256: ry[64]; 320: ex[64]; 384: ey[64];
// 448: out_c_f[64*3]; 640: prob1[64*3]; 832: prob2[64*3]

#define F4E(v_, e_) ((e_)==0?(v_).x:((e_)==1?(v_).y:((e_)==2?(v_).z:(v_).w)))

typedef __attribute__((ext_vector_type(8))) short bf16x8;
typedef __attribute__((ext_vector_type(4))) float f32x4;

__device__ __forceinline__ unsigned short f2bf(float f){
    union { float f; unsigned int u; } v; v.f = f;
    unsigned int r = v.u + 0x7fffu + ((v.u >> 16) & 1u);
    return (unsigned short)(r >> 16);
}
__device__ __forceinline__ float bf2f(unsigned short h){
    union { unsigned int u; float f; } v; v.u = ((unsigned int)h) << 16;
    return v.f;
}
__device__ __forceinline__ void sw2(unsigned short* ph, unsigned short* pl, int idx, float f){
    unsigned short h = f2bf(f);
    ph[idx] = h;
    pl[idx] = f2bf(f - bf2f(h));
}
__device__ __forceinline__ void sw2x2(unsigned short* ph, unsigned short* pl, int idx, float f0, float f1){
    unsigned short h0 = f2bf(f0), h1 = f2bf(f1);
    ushort2 hh; hh.x = h0; hh.y = h1;
    *(ushort2*)(ph + idx) = hh;
    ushort2 ll; ll.x = f2bf(f0 - bf2f(h0)); ll.y = f2bf(f1 - bf2f(h1));
    *(ushort2*)(pl + idx) = ll;
}

#define LD8(P_, row_, kb_) (*(const bf16x8*)((const char*)(P_) + (size_t)(row_)*144 + (kb_)))

// K=64 tile MAC: acc += A[ar..ar+15][0:64] * B[br..br+15][0:64]^T  (hi/lo 3-combo)
__device__ __forceinline__ f32x4 mm64(
    const unsigned short* Ah, const unsigned short* Al,
    const unsigned short* Bh, const unsigned short* Bl,
    int ar, int br, int lrow, int lkb, f32x4 acc)
{
    const int ra = ar + lrow, rb = br + lrow;
    bf16x8 ah0 = LD8(Ah, ra, lkb), ah1 = LD8(Ah, ra, lkb+64);
    bf16x8 al0 = LD8(Al, ra, lkb), al1 = LD8(Al, ra, lkb+64);
    bf16x8 bh0 = LD8(Bh, rb, lkb), bh1 = LD8(Bh, rb, lkb+64);
    bf16x8 bl0 = LD8(Bl, rb, lkb), bl1 = LD8(Bl, rb, lkb+64);
    acc = __builtin_amdgcn_mfma_f32_16x16x32_bf16(ah0, bh0, acc, 0,0,0);
    acc = __builtin_amdgcn_mfma_f32_16x16x32_bf16(ah1, bh1, acc, 0,0,0);
    acc = __builtin_amdgcn_mfma_f32_16x16x32_bf16(ah0, bl0, acc, 0,0,0);
    acc = __builtin_amdgcn_mfma_f32_16x16x32_bf16(ah1, bl1, acc, 0,0,0);
    acc = __builtin_amdgcn_mfma_f32_16x16x32_bf16(al0, bh0, acc, 0,0,0);
    acc = __builtin_amdgcn_mfma_f32_16x16x32_bf16(al1, bh1, acc, 0,0,0);
    return acc;
}

// =================== K1: MFMA bf16-hi/lo fused MLP, 512 threads / 8 waves ===================
__global__ __launch_bounds__(512) void k1_fused(
    const float* __restrict__ x, const float* __restrict__ y,
    const float* __restrict__ w11_1, const float* __restrict__ b11_1,
    const float* __restrict__ w11_2, const float* __restrict__ b11_2,
    const float* __restrict__ w12_1, const float* __restrict__ b12_1,
    const float* __restrict__ w12_2, const float* __restrict__ b12_2,
    float* __restrict__ out_x, float* __restrict__ out_y,
    float* __restrict__ mean_part)
{
    const int b = blockIdx.x >> 2, tile = blockIdx.x & 3;
    const int t = threadIdx.x;
    const int lane = t & 63, wv = t >> 6;          // wv 0..7
    const int lrow = lane & 15;
    const int lkb  = (lane >> 4) * 16;
    const int row0g = b*NS + tile*64;

    __shared__ unsigned short XYh[9216], XYl[9216];   // 128 rows
    __shared__ unsigned short W1h[4608], W1l[4608];   // 64 rows
    __shared__ unsigned short W2h[4608], W2l[4608];
    __shared__ unsigned short Hh [9216], Hl [9216];
    __shared__ unsigned short Oh [9216], Ol [9216];
    __shared__ float msum[8*68];

    // ---- P0: stage XY + W1^T + W2^T ----
    #pragma unroll
    for (int u=0;u<4;u++){
        int id = t + 512*u;                 // 2048 float4
        int r = id>>4, c0 = (id&15)*4;
        const float* src = (r < 64) ? (x + ((size_t)(row0g + r))*ND)
                                    : (y + ((size_t)(row0g + r - 64))*ND);
        float4 v = *(const float4*)(src + c0);
        sw2x2(XYh, XYl, r*72 + c0,   v.x, v.y);
        sw2x2(XYh, XYl, r*72 + c0+2, v.z, v.w);
    }
    {
        int rp = t>>4, c0 = (t&15)*4;       // 512 row-pair jobs
        float4 a0 = *(const float4*)(w11_1 + (size_t)(2*rp  )*64 + c0);
        float4 a1 = *(const float4*)(w11_1 + (size_t)(2*rp+1)*64 + c0);
        float4 b0 = *(const float4*)(w11_2 + (size_t)(2*rp  )*64 + c0);
        float4 b1 = *(const float4*)(w11_2 + (size_t)(2*rp+1)*64 + c0);
        #pragma unroll
        for (int i2=0;i2<4;i2++){
            sw2x2(W1h, W1l, (c0+i2)*72 + 2*rp, F4E(a0,i2), F4E(a1,i2));
            sw2x2(W2h, W2l, (c0+i2)*72 + 2*rp, F4E(b0,i2), F4E(b1,i2));
        }
    }
    __syncthreads();

    // ---- P1: G1  H = relu(XY @ W1 + b1) : wave w -> rows 16w ----
    {
        const int ar = 16*wv;
        #pragma unroll
        for (int jt=0; jt<4; jt++){
            float bb = b11_1[jt*16 + lrow];
            f32x4 acc = {bb,bb,bb,bb};
            acc = mm64(XYh, XYl, W1h, W1l, ar, jt*16, lrow, lkb, acc);
            #pragma unroll
            for (int e=0;e<4;e++){
                int row = ar + (lane>>4)*4 + e;
                int col = jt*16 + lrow;
                sw2(Hh, Hl, row*72 + col, fmaxf(acc[e], 0.f));
            }
        }
    }
    __syncthreads();

    // ---- P2: stage w12_1^T half0 -> XY region; G2  O = H @ W2 + b2 ----
    #pragma unroll
    for (int u=0;u<2;u++){
        int id = t + 512*u;                 // 1024 row-pair jobs
        int krp = id>>5, c0 = (id&31)*4;
        float4 v0 = *(const float4*)(w12_1 + (size_t)(2*krp  )*NH + c0);
        float4 v1 = *(const float4*)(w12_1 + (size_t)(2*krp+1)*NH + c0);
        #pragma unroll
        for (int i2=0;i2<4;i2++)
            sw2x2(XYh, XYl, (c0+i2)*72 + 2*krp, F4E(v0,i2), F4E(v1,i2));
    }
    {
        const int ar = 16*wv;
        #pragma unroll
        for (int jt=0; jt<4; jt++){
            float bb = b11_2[jt*16 + lrow];
            f32x4 acc = {bb,bb,bb,bb};
            acc = mm64(Hh, Hl, W2h, W2l, ar, jt*16, lrow, lkb, acc);
            #pragma unroll
            for (int e=0;e<4;e++){
                int row = ar + (lane>>4)*4 + e;
                int col = jt*16 + lrow;
                float v = acc[e];
                sw2(Oh, Ol, row*72 + col, v);
                float* dst = (row < 64) ? out_x : out_y;
                dst[((size_t)(row0g + (row & 63)))*NH2 + col] = v;
            }
        }
    }
    __syncthreads();

    // ---- P3: G3 pass0: wave w -> (row-tile rt=w&3, col-tiles 4*(w>>2)+q) ----
    const int rt = wv & 3, cq = wv >> 2;
    f32x4 acc3[4];
    #pragma unroll
    for (int q=0; q<4; q++){
        float bb = b12_1[(4*cq+q)*16 + lrow];
        f32x4 v = {bb,bb,bb,bb};
        acc3[q] = v;
    }
    #pragma unroll
    for (int q=0; q<4; q++)
        acc3[q] = mm64(Oh, Ol, XYh, XYl, 16*rt, 16*(4*cq+q), lrow, lkb, acc3[q]);
    __syncthreads();

    // ---- P4: stage w12_1^T half1 -> XY; w12_2^T halves -> W2(h0)/W1(h1) ----
    #pragma unroll
    for (int u=0;u<2;u++){
        int id = t + 512*u;
        int krp = id>>5, c0 = (id&31)*4;
        float4 v0 = *(const float4*)(w12_1 + (size_t)(64+2*krp  )*NH + c0);
        float4 v1 = *(const float4*)(w12_1 + (size_t)(64+2*krp+1)*NH + c0);
        #pragma unroll
        for (int i2=0;i2<4;i2++)
            sw2x2(XYh, XYl, (c0+i2)*72 + 2*krp, F4E(v0,i2), F4E(v1,i2));
    }
    {
        int krp = t>>4, c0 = (t&15)*4;      // 512 row-pair jobs
        float4 h0a = *(const float4*)(w12_2 + (size_t)(2*krp  )*NH2 + c0);
        float4 h0b = *(const float4*)(w12_2 + (size_t)(2*krp+1)*NH2 + c0);
        float4 h1a = *(const float4*)(w12_2 + (size_t)(64+2*krp  )*NH2 + c0);
        float4 h1b = *(const float4*)(w12_2 + (size_t)(64+2*krp+1)*NH2 + c0);
        #pragma unroll
        for (int i2=0;i2<4;i2++){
            sw2x2(W2h, W2l, (c0+i2)*72 + 2*krp, F4E(h0a,i2), F4E(h0b,i2));
            sw2x2(W1h, W1l, (c0+i2)*72 + 2*krp, F4E(h1a,i2), F4E(h1b,i2));
        }
    }
    __syncthreads();

    // ---- P5: G3 pass1 + epi -> H1 into H region ----
    #pragma unroll
    for (int q=0; q<4; q++)
        acc3[q] = mm64(Oh, Ol, XYh, XYl, 64 + 16*rt, 16*(4*cq+q), lrow, lkb, acc3[q]);
    #pragma unroll
    for (int q=0; q<4; q++){
        #pragma unroll
        for (int e=0;e<4;e++){
            int row = 16*rt + (lane>>4)*4 + e;        // sample 0..63
            int col = 16*(4*cq+q) + lrow;             // 0..127
            float v = fmaxf(acc3[q][e], 0.f);
            int idx = (col < 64) ? (row*72 + col) : ((64+row)*72 + (col-64));
            sw2(Hh, Hl, idx, v);
        }
    }
    __syncthreads();

    // ---- P6: G4: wave w -> (rt, cols (2*cq+q)*16) ----
    {
        f32x4 acc2[2];
        #pragma unroll
        for (int q=0; q<2; q++){
            const int jc = 2*cq + q;
            float bb = b12_2[jc*16 + lrow];
            f32x4 v = {bb,bb,bb,bb};
            acc2[q] = v;
            acc2[q] = mm64(Hh, Hl, W2h, W2l, 16*rt,      16*jc, lrow, lkb, acc2[q]);
            acc2[q] = mm64(Hh, Hl, W1h, W1l, 64 + 16*rt, 16*jc, lrow, lkb, acc2[q]);
        }
        #pragma unroll
        for (int q=0; q<2; q++){
            const int jc = 2*cq + q;
            float s = fmaxf(acc2[q][0],0.f) + fmaxf(acc2[q][1],0.f)
                    + fmaxf(acc2[q][2],0.f) + fmaxf(acc2[q][3],0.f);
            s += __shfl_down(s, 32);
            s += __shfl_down(s, 16);
            if (lane < 16) msum[wv*68 + jc*16 + lane] = s;
        }
    }
    __syncthreads();
    if (t < 64){
        const int w0 = (t>>5)*4;
        float ss = msum[(w0+0)*68 + t] + msum[(w0+1)*68 + t]
                 + msum[(w0+2)*68 + t] + msum[(w0+3)*68 + t];
        mean_part[((size_t)(b*4+tile))*64 + t] = ss;
    }
}

// =================== K2AB: center-first MFMA gram + Neumann/Horner solve ===================
__global__ __launch_bounds__(256) void k2ab(
    const float* __restrict__ fx, const float* __restrict__ fy,
    const float* __restrict__ x, const float* __restrict__ y,
    float* __restrict__ wbuf)
{
    const int bs = blockIdx.x;
    const int side = bs & 1, b = bs >> 1;
    const float* feat = side ? fy : fx;
    const float* targ = side ? x : y;
    float* wb = wbuf + (size_t)bs*WSTRIDE;
    const int t = threadIdx.x;
    const int lane = t & 63, wv = t >> 6;
    const int lrow = lane & 15;
    const int lkb  = (lane >> 4) * 16;
    const float inv256 = 1.0f/256.0f;

    __shared__ float Wf[64*68];
    __shared__ float Rf[64*68];
    __shared__ unsigned short Zh[4608], Zl[4608], Th[4608], Tl[4608];
    __shared__ unsigned short Eh[4608], El[4608];
    __shared__ unsigned short Wth[2][4608], Wtl[2][4608];
    __shared__ float cspA[16*68], cspB[16*68];
    __shared__ float szs[64], sts[64];
    __shared__ float sc[8], red4[4];

    // ---- Phase A: raw col sums of Z,T and sum T^2 ----
    {
        float szp0=0.f,szp1=0.f,szp2=0.f,szp3=0.f;
        float stp0=0.f,stp1=0.f,stp2=0.f,stp3=0.f;
        float tsq=0.f;
        for (int c=0;c<4;c++){
            #pragma unroll
            for (int u=0;u<4;u++){
                int id = t + 256*u;
                int r = id>>4, c0 = (id&15)*4;
                float4 v = *(const float4*)(feat + ((size_t)(b*NS + c*64 + r))*NH2 + c0);
                float4 w = *(const float4*)(targ + ((size_t)(b*NS + c*64 + r))*ND + c0);
                szp0+=v.x; szp1+=v.y; szp2+=v.z; szp3+=v.w;
                stp0+=w.x; stp1+=w.y; stp2+=w.z; stp3+=w.w;
                tsq += w.x*w.x + w.y*w.y + w.z*w.z + w.w*w.w;
            }
        }
        const int g2 = t>>4, c0 = (t&15)*4;
        cspA[g2*68 + c0+0] = szp0; cspA[g2*68 + c0+1] = szp1;
        cspA[g2*68 + c0+2] = szp2; cspA[g2*68 + c0+3] = szp3;
        cspB[g2*68 + c0+0] = stp0; cspB[g2*68 + c0+1] = stp1;
        cspB[g2*68 + c0+2] = stp2; cspB[g2*68 + c0+3] = stp3;
        float tq = tsq;
        #pragma unroll
        for (int off=32; off; off>>=1) tq += __shfl_down(tq, off);
        if (lane==0) red4[wv] = tq;
    }
    __syncthreads();
    if (t < 64){
        float sa=0.f, sb=0.f;
        #pragma unroll
        for (int g2=0; g2<16; g2++){ sa += cspA[g2*68+t]; sb += cspB[g2*68+t]; }
        szs[t] = sa; sts[t] = sb;
        float s2 = sa*sa;
        #pragma unroll
        for (int off=32; off; off>>=1) s2 += __shfl_down(s2, off);
        if (t==0) sc[2] = s2;
    }
    if (t==0) sc[1] = red4[0]+red4[1]+red4[2]+red4[3];
    __syncthreads();

    // ---- Phase B: gram of CENTERED Z, Rc = Zc^T T ----
    f32x4 accA[4], accR[4];
    #pragma unroll
    for (int jt=0;jt<4;jt++){
        f32x4 z = {0.f,0.f,0.f,0.f};
        accA[jt]=z; accR[jt]=z;
    }
    for (int c=0;c<4;c++){
        if (c) __syncthreads();
        #pragma unroll
        for (int u=0;u<4;u++){
            int id = t + 256*u;
            int r = id>>4, c0 = (id&15)*4;
            float4 v = *(const float4*)(feat + ((size_t)(b*NS + c*64 + r))*NH2 + c0);
            float4 w = *(const float4*)(targ + ((size_t)(b*NS + c*64 + r))*ND + c0);
            v.x -= szs[c0+0]*inv256; v.y -= szs[c0+1]*inv256;
            v.z -= szs[c0+2]*inv256; v.w -= szs[c0+3]*inv256;
            sw2(Zh,Zl,(c0+0)*72+r, v.x); sw2(Zh,Zl,(c0+1)*72+r, v.y);
            sw2(Zh,Zl,(c0+2)*72+r, v.z); sw2(Zh,Zl,(c0+3)*72+r, v.w);
            sw2(Th,Tl,(c0+0)*72+r, w.x); sw2(Th,Tl,(c0+1)*72+r, w.y);
            sw2(Th,Tl,(c0+2)*72+r, w.z); sw2(Th,Tl,(c0+3)*72+r, w.w);
        }
        __syncthreads();
        #pragma unroll
        for (int jt=0;jt<4;jt++){
            accA[jt] = mm64(Zh,Zl,Zh,Zl, 16*wv, 16*jt, lrow, lkb, accA[jt]);
            accR[jt] = mm64(Zh,Zl,Th,Tl, 16*wv, 16*jt, lrow, lkb, accR[jt]);
        }
    }
    {
        const int gi0 = 16*wv + (lane>>4)*4;
        #pragma unroll
        for (int jt=0;jt<4;jt++){
            #pragma unroll
            for (int e=0;e<4;e++){
                Wf[(gi0+e)*68 + 16*jt + lrow] = accA[jt][e];
                Rf[(gi0+e)*68 + 16*jt + lrow] = accR[jt][e];
            }
        }
    }
    __syncthreads();
    if (t<64){
        float dg = Wf[t*68+t];
        #pragma unroll
        for (int off=32; off; off>>=1) dg += __shfl_down(dg, off);
        if (t==0){
            float zn2 = dg + sc[2]*inv256;
            sc[0] = 1.0f/sqrtf(zn2);
            sc[1] = 1.0f/sqrtf(sc[1]);
        }
    }
    __syncthreads();
    const float zinv = sc[0], tinv = sc[1];
    const float z2 = zinv*zinv, zt = zinv*tinv;
    const float i23 = 2.0f/3.0f, i13 = 1.0f/3.0f;
    const int i = t>>2, qd = t&3;
    {
        #pragma unroll
        for (int q=0;q<4;q++){
            const int j = qd*16 + q*4;
            float4 a4 = *(const float4*)(Wf + i*68 + j);
            float e0 = i23*z2*a4.x - ((i==j  ) ? i13 : 0.f);
            float e1 = i23*z2*a4.y - ((i==j+1) ? i13 : 0.f);
            float e2 = i23*z2*a4.z - ((i==j+2) ? i13 : 0.f);
            float e3 = i23*z2*a4.w - ((i==j+3) ? i13 : 0.f);
            sw2x2(Eh, El, i*72 + j,   e0, e1);
            sw2x2(Eh, El, i*72 + j+2, e2, e3);
            float4 rv = *(float4*)(Rf + i*68 + j);
            float r0 = i23*zt*rv.x;
            float r1 = i23*zt*rv.y;
            float r2 = i23*zt*rv.z;
            float r3 = i23*zt*rv.w;
            *(float4*)(Rf + i*68 + j) = make_float4(r0,r1,r2,r3);
            sw2(Wth[0], Wtl[0], (j  )*72 + i, r0);
            sw2(Wth[0], Wtl[0], (j+1)*72 + i, r1);
            sw2(Wth[0], Wtl[0], (j+2)*72 + i, r2);
            sw2(Wth[0], Wtl[0], (j+3)*72 + i, r3);
        }
    }
    __syncthreads();

    int cur = 0;
    for (int n=0; n<12; n++){
        f32x4 acc[4];
        #pragma unroll
        for (int jt=0; jt<4; jt++){
            f32x4 zz = {0.f,0.f,0.f,0.f};
            acc[jt] = mm64(Eh, El, Wth[cur], Wtl[cur], 16*wv, jt*16, lrow, lkb, zz);
        }
        const int gi0 = 16*wv + (lane>>4)*4;
        #pragma unroll
        for (int jt=0; jt<4; jt++){
            const int gj = jt*16 + lrow;
            float w0 = Rf[(gi0  )*68 + gj] - acc[jt][0];
            float w1 = Rf[(gi0+1)*68 + gj] - acc[jt][1];
            float w2 = Rf[(gi0+2)*68 + gj] - acc[jt][2];
            float w3 = Rf[(gi0+3)*68 + gj] - acc[jt][3];
            sw2x2(Wth[cur^1], Wtl[cur^1], gj*72 + gi0,   w0, w1);
            sw2x2(Wth[cur^1], Wtl[cur^1], gj*72 + gi0+2, w2, w3);
            if (n == 11){
                Wf[(gi0  )*68 + gj] = w0;  wb[(gi0  )*64 + gj] = w0;
                Wf[(gi0+1)*68 + gj] = w1;  wb[(gi0+1)*64 + gj] = w1;
                Wf[(gi0+2)*68 + gj] = w2;  wb[(gi0+2)*64 + gj] = w2;
                Wf[(gi0+3)*68 + gj] = w3;  wb[(gi0+3)*64 + gj] = w3;
            }
        }
        cur ^= 1;
        __syncthreads();
    }

    if (t < 64){
        float s = 0.f;
        for (int i2=0; i2<64; i2++) s += szs[i2]*Wf[i2*68 + t];
        wb[4096+t] = (tinv*sts[t] - zinv*s) * inv256;
    }
    if (t==0){ wb[4160] = zinv; wb[4161] = tinv; }
}

// =================== KRG: fused residual + Renyi Gram, 512 threads / 8 waves ===================
__global__ __launch_bounds__(512) void kRG(
    const float* __restrict__ fx, const float* __restrict__ fy,
    const float* __restrict__ x, const float* __restrict__ y,
    const float* __restrict__ wbuf,
    float* __restrict__ part3, float* __restrict__ dout)
{
    const int blk = blockIdx.x;
    const int jh = blk & 1;
    const int b = (blk >> 1) & (NB-1);
    const int side = (blk >> 1) >> 6;
    const float* feat = side ? fy : fx;
    const float* targ = side ? x : y;
    const float* bmat = side ? y : x;
    const float* wb = wbuf + (size_t)(b*2+side)*WSTRIDE;
    const int t = threadIdx.x;
    const int lane = t & 63, wv = t >> 6;          // wv 0..7
    const int lrow = lane & 15, lkb = (lane>>4)*16;

    __shared__ unsigned short resA[256*72];
    __shared__ unsigned short tgB [256*72];
    __shared__ unsigned short Zh[2*4608], Zl[2*4608];
    __shared__ unsigned short Wth[4608], Wtl[4608];
    __shared__ float c0s[64];
    __shared__ float nAs[256], nBs[256];
    __shared__ float red[8][3];
    __shared__ float lred[8];

    #pragma unroll
    for (int u=0;u<2;u++){
        int id = t + 512*u;                  // 1024 float4 over W rows k
        int k = id>>4, c0 = (id&15)*4;
        float4 v = *(const float4*)(wb + (size_t)k*64 + c0);
        sw2(Wth, Wtl, (c0+0)*72 + k, v.x);
        sw2(Wth, Wtl, (c0+1)*72 + k, v.y);
        sw2(Wth, Wtl, (c0+2)*72 + k, v.z);
        sw2(Wth, Wtl, (c0+3)*72 + k, v.w);
    }
    if (t<64) c0s[t] = wb[4096+t];
    const float zinv = wb[4160], tinv = wb[4161];
    #pragma unroll
    for (int u=0;u<8;u++){
        int id = t + 512*u;                  // 4096 float4
        int r = id>>4, c0 = (id&15)*4;
        float4 v = *(const float4*)(bmat + ((size_t)(b*NS+r))*ND + c0);
        ushort4 h;
        h.x=f2bf(v.x); h.y=f2bf(v.y); h.z=f2bf(v.z); h.w=f2bf(v.w);
        *(ushort4*)(tgB + r*72 + c0) = h;
    }
    #pragma unroll
    for (int u=0;u<2;u++){
        int id = t + 512*u;                  // 1024 float4, chunk 0
        int r = id>>4, c0 = (id&15)*4;
        float4 v = *(const float4*)(feat + ((size_t)(b*NS + r))*NH2 + c0);
        sw2x2(Zh, Zl, r*72+c0,   v.x, v.y);
        sw2x2(Zh, Zl, r*72+c0+2, v.z, v.w);
    }
    __syncthreads();

    // ---- residual: 4 chunks of 64 rows; wave w -> (row-tile w&3, col-tiles 2*(w>>2)+q) ----
    const int rt = wv & 3, cq = wv >> 2;
    float lacc = 0.f;
    for (int c=0; c<4; c++){
        if (c < 3){
            unsigned short* zh = Zh + ((c+1)&1)*4608;
            unsigned short* zl = Zl + ((c+1)&1)*4608;
            #pragma unroll
            for (int u=0;u<2;u++){
                int id = t + 512*u;
                int r = id>>4, c0 = (id&15)*4;
                float4 v = *(const float4*)(feat + ((size_t)(b*NS + (c+1)*64 + r))*NH2 + c0);
                sw2x2(zh, zl, r*72+c0,   v.x, v.y);
                sw2x2(zh, zl, r*72+c0+2, v.z, v.w);
            }
        }
        const unsigned short* zh = Zh + (c&1)*4608;
        const unsigned short* zl = Zl + (c&1)*4608;
        f32x4 acc[2];
        #pragma unroll
        for (int q=0; q<2; q++){
            f32x4 zz = {0.f,0.f,0.f,0.f};
            acc[q] = mm64(zh, zl, Wth, Wtl, 16*rt, 16*(2*cq+q), lrow, lkb, zz);
        }
        const int r0 = 16*rt + (lane>>4)*4;
        #pragma unroll
        for (int q=0; q<2; q++){
            const int gj = 16*(2*cq+q) + lrow;
            const float cc = c0s[gj];
            #pragma unroll
            for (int e=0;e<4;e++){
                const int grow = c*64 + r0 + e;
                float qv = targ[((size_t)(b*NS+grow))*ND + gj];
                float rr = tinv*qv - zinv*acc[q][e] - cc;
                lacc += rr*rr;
                resA[grow*72 + gj] = f2bf(rr);
            }
        }
        __syncthreads();
    }

    {
        float l = lacc;
        #pragma unroll
        for (int off=32; off; off>>=1) l += __shfl_down(l, off);
        if (lane==0) lred[wv] = l;
    }
    if (t < 256){
        float sa=0.f, sb=0.f;
        #pragma unroll
        for (int j8=0;j8<8;j8++){
            bf16x8 va = *(const bf16x8*)((const char*)resA + (size_t)t*144 + j8*16);
            bf16x8 vb = *(const bf16x8*)((const char*)tgB  + (size_t)t*144 + j8*16);
            #pragma unroll
            for (int e2=0;e2<8;e2++){
                float fa = bf2f((unsigned short)va[e2]);
                float fb = bf2f((unsigned short)vb[e2]);
                sa += fa*fa; sb += fb*fb;
            }
        }
        nAs[t] = sa; nBs[t] = sb;
    }
    __syncthreads();
    if (t==0 && jh==0){
        float ls = 0.f;
        #pragma unroll
        for (int w=0;w<8;w++) ls += lred[w];
        dout[(side?256:192)+b] = ls;
    }

    // ---- Gram + exp: wave w -> i-tiles i0 = 32w+16it (it<2) ----
    const char* pA = (const char*)resA;
    const char* pB = (const char*)tgB;
    const f32x4 zero4 = {0.f, 0.f, 0.f, 0.f};
    const float CEXP = -2.8853900817779268f;

    float Sa=0.f, Sb=0.f, Sab=0.f;
    #pragma unroll
    for (int it=0; it<2; it++){
        const int i0 = wv*32 + it*16;
        const int arow = i0 + lrow;
        bf16x8 aA0 = *(const bf16x8*)(pA + arow*144 + lkb);
        bf16x8 aA1 = *(const bf16x8*)(pA + arow*144 + lkb + 64);
        bf16x8 aB0 = *(const bf16x8*)(pB + arow*144 + lkb);
        bf16x8 aB1 = *(const bf16x8*)(pB + arow*144 + lkb + 64);
        float nAi[4], nBi[4];
        #pragma unroll
        for (int e=0;e<4;e++){
            int gi = i0 + (lane>>4)*4 + e;
            nAi[e] = nAs[gi]; nBi[e] = nBs[gi];
        }
        #pragma unroll
        for (int jt=0; jt<8; jt++){
            const int j0 = jh*128 + jt*16;
            const int brow = j0 + lrow;
            bf16x8 bA0 = *(const bf16x8*)(pA + brow*144 + lkb);
            bf16x8 bA1 = *(const bf16x8*)(pA + brow*144 + lkb + 64);
            bf16x8 bB0 = *(const bf16x8*)(pB + brow*144 + lkb);
            bf16x8 bB1 = *(const bf16x8*)(pB + brow*144 + lkb + 64);
            f32x4 cA = __builtin_amdgcn_mfma_f32_16x16x32_bf16(aA0, bA0, zero4, 0, 0, 0);
            cA = __builtin_amdgcn_mfma_f32_16x16x32_bf16(aA1, bA1, cA, 0, 0, 0);
            f32x4 cB = __builtin_amdgcn_mfma_f32_16x16x32_bf16(aB0, bB0, zero4, 0, 0, 0);
            cB = __builtin_amdgcn_mfma_f32_16x16x32_bf16(aB1, bB1, cB, 0, 0, 0);
            const int gj = j0 + lrow;
            const float nAj = nAs[gj], nBj = nBs[gj];
            #pragma unroll
            for (int e=0;e<4;e++){
                const int gi = i0 + (lane>>4)*4 + e;
                const float dda = (gi==gj) ? 0.f : (nAi[e] + nAj - 2.f*cA[e]);
                const float ddb = (gi==gj) ? 0.f : (nBi[e] + nBj - 2.f*cB[e]);
                const float ka2 = exp2f(CEXP*dda);
                const float kb2 = exp2f(CEXP*ddb);
                Sa += ka2; Sb += kb2; Sab += ka2*kb2;
            }
        }
    }
    #pragma unroll
    for (int off=32; off; off>>=1){
        Sa += __shfl_down(Sa,off); Sb += __shfl_down(Sb,off); Sab += __shfl_down(Sab,off);
    }
    if (lane==0){ red[wv][0]=Sa; red[wv][1]=Sb; red[wv][2]=Sab; }
    __syncthreads();
    if (t==0){
        float s0=0.f, s1=0.f, s2=0.f;
        #pragma unroll
        for (int w=0;w<8;w++){ s0 += red[w][0]; s1 += red[w][1]; s2 += red[w][2]; }
        float* o = part3 + (size_t)blk*3;
        o[0] = s0; o[1] = s1; o[2] = s2;
    }
}

// =================== K4 ===================
__global__ __launch_bounds__(64) void k4_final(
    const float* __restrict__ mean_part, const float* __restrict__ part3,
    const float* __restrict__ wc1, const float* __restrict__ bc1,
    const float* __restrict__ bn_gamma, const float* __restrict__ bn_beta,
    const float* __restrict__ w2, const float* __restrict__ b2,
    const float* __restrict__ wc2, const float* __restrict__ bc2,
    float* __restrict__ dout)
{
    const int t = threadIdx.x;
    __shared__ float ic[64][5];
    __shared__ float mu[5], iv[5];

    float o0 = bc1[0], o1 = bc1[1], o2 = bc1[2];
    for (int c=0;c<64;c++){
        float mv = mean_part[(t*4+0)*64+c] + mean_part[(t*4+1)*64+c]
                 + mean_part[(t*4+2)*64+c] + mean_part[(t*4+3)*64+c];
        mv *= (1.0f/256.0f);
        o0 += mv*wc1[c*3+0]; o1 += mv*wc1[c*3+1]; o2 += mv*wc1[c*3+2];
    }
    dout[t*3+0]=o0; dout[t*3+1]=o1; dout[t*3+2]=o2;
    {
        float m = fmaxf(o0,fmaxf(o1,o2));
        float e0=__expf(o0-m), e1=__expf(o1-m), e2=__expf(o2-m);
        float inv = 1.f/(e0+e1+e2);
        dout[640+t*3+0]=e0*inv; dout[640+t*3+1]=e1*inv; dout[640+t*3+2]=e2*inv;
    }
    float exy[2];
    #pragma unroll
    for (int side=0; side<2; side++){
        const float* pp = part3 + (size_t)((side*NB + t)*2)*3;
        float Sa = pp[0]+pp[3];
        float Sb = pp[1]+pp[4];
        float Sab= pp[2]+pp[5];
        float Hx  = 16.f - log2f(Sa);
        float Hy  = 16.f - log2f(Sb);
        float Hxy = 16.f - log2f(Sab);
        float mi = (Hx + Hy - Hxy) / fmaxf(Hx, Hy);
        dout[(side?384:320)+t] = mi;
        exy[side] = mi;
    }
    ic[t][0]=o0; ic[t][1]=o1; ic[t][2]=o2; ic[t][3]=exy[0]; ic[t][4]=exy[1];
    __syncthreads();
    if (t<5){
        float m=0.f;
        for (int bb=0;bb<64;bb++) m += ic[bb][t];
        m *= (1.f/64.f);
        float v=0.f;
        for (int bb=0;bb<64;bb++){ float d=ic[bb][t]-m; v+=d*d; }
        v *= (1.f/64.f);
        mu[t]=m; iv[t]=1.f/sqrtf(v+1e-5f);
    }
    __syncthreads();
    float vn[5];
    #pragma unroll
    for (int c=0;c<5;c++) vn[c] = (ic[t][c]-mu[c])*iv[c]*bn_gamma[c]+bn_beta[c];
    float q0=bc2[0], q1=bc2[1], q2=bc2[2];
    for (int j=0;j<64;j++){
        float hh = b2[j];
        #pragma unroll
        for (int c=0;c<5;c++) hh += vn[c]*w2[c*64+j];
        hh = fmaxf(hh,0.f);
        q0 += hh*wc2[j*3+0]; q1 += hh*wc2[j*3+1]; q2 += hh*wc2[j*3+2];
    }
    dout[448+t*3+0]=q0; dout[448+t*3+1]=q1; dout[448+t*3+2]=q2;
    float m = fmaxf(q0,fmaxf(q1,q2));
    float e0=__expf(q0-m), e1=__expf(q1-m), e2=__expf(q2-m);
    float inv=1.f/(e0+e1+e2);
    dout[832+t*3+0]=e0*inv; dout[832+t*3+1]=e1*inv; dout[832+t*3+2]=e2*inv;
}

extern "C" void kernel_launch(void* const* d_in, const int* in_sizes, int n_in,
                              void* d_out, int out_size, void* d_ws, size_t ws_size,
                              hipStream_t stream)
{
    const float* x     = (const float*)d_in[0];
    const float* y     = (const float*)d_in[1];
    const float* w11_1 = (const float*)d_in[2];
    const float* b11_1 = (const float*)d_in[3];
    const float* w11_2 = (const float*)d_in[4];
    const float* b11_2 = (const float*)d_in[5];
    const float* w12_1 = (const float*)d_in[6];
    const float* b12_1 = (const float*)d_in[7];
    const float* w12_2 = (const float*)d_in[8];
    const float* b12_2 = (const float*)d_in[9];
    const float* wc1   = (const float*)d_in[10];
    const float* bc1   = (const float*)d_in[11];
    const float* bn_g  = (const float*)d_in[12];
    const float* bn_b  = (const float*)d_in[13];
    const float* w2    = (const float*)d_in[14];
    const float* b2    = (const float*)d_in[15];
    const float* wc2   = (const float*)d_in[16];
    const float* bc2   = (const float*)d_in[17];

    float* ws   = (float*)d_ws;
    float* dout = (float*)d_out;
    float* out_x = ws;                           // 1,048,576 floats
    float* out_y = ws + 1048576;
    float* mean_part = ws + 2097152;             // 16384
    float* part3 = mean_part + 16384;            // 768 (alloc 3840)
    float* wbuf  = part3 + 3840;                 // 128*4224 = 540672

    hipLaunchKernelGGL(k1_fused, dim3(NB*4), dim3(512), 0, stream,
        x,y,w11_1,b11_1,w11_2,b11_2,w12_1,b12_1,w12_2,b12_2,
        out_x,out_y,mean_part);
    hipLaunchKernelGGL(k2ab, dim3(2*NB), dim3(256), 0, stream,
        out_x,out_y,x,y,wbuf);
    hipLaunchKernelGGL(kRG, dim3(NB*2*2), dim3(512), 0, stream,
        out_x,out_y,x,y,wbuf,part3,dout);
    hipLaunchKernelGGL(k4_final, dim3(1), dim3(64), 0, stream,
        mean_part,part3,wc1,bc1,bn_g,bn_b,w2,b2,wc2,bc2,dout);
}

// Round 14
// 76.810 us; speedup vs baseline: 1.2912x; 1.0047x over previous
//
#include <hip/hip_runtime.h>
#include <math.h>

#define NB 64
#define NS 256
#define ND 64
#define NH2 64
#define NH 128
#define WSTRIDE 4224

// d_out layout (floats):
// 0: out_c[64*3]; 192: rx[64]; 256: ry[64]; 320: ex[64]; 384: ey[64];
// 448: out_c_f[64*3]; 640: prob1[64*3]; 832: prob2[64*3]

#define F4E(v_, e_) ((e_)==0?(v_).x:((e_)==1?(v_).y:((e_)==2?(v_).z:(v_).w)))

typedef __attribute__((ext_vector_type(8))) short bf16x8;
typedef __attribute__((ext_vector_type(4))) float f32x4;

__device__ __forceinline__ unsigned short f2bf(float f){
    union { float f; unsigned int u; } v; v.f = f;
    unsigned int r = v.u + 0x7fffu + ((v.u >> 16) & 1u);
    return (unsigned short)(r >> 16);
}
__device__ __forceinline__ float bf2f(unsigned short h){
    union { unsigned int u; float f; } v; v.u = ((unsigned int)h) << 16;
    return v.f;
}
__device__ __forceinline__ void sw2(unsigned short* ph, unsigned short* pl, int idx, float f){
    unsigned short h = f2bf(f);
    ph[idx] = h;
    pl[idx] = f2bf(f - bf2f(h));
}
__device__ __forceinline__ void sw2x2(unsigned short* ph, unsigned short* pl, int idx, float f0, float f1){
    unsigned short h0 = f2bf(f0), h1 = f2bf(f1);
    ushort2 hh; hh.x = h0; hh.y = h1;
    *(ushort2*)(ph + idx) = hh;
    ushort2 ll; ll.x = f2bf(f0 - bf2f(h0)); ll.y = f2bf(f1 - bf2f(h1));
    *(ushort2*)(pl + idx) = ll;
}

#define LD8(P_, row_, kb_) (*(const bf16x8*)((const char*)(P_) + (size_t)(row_)*144 + (kb_)))

// K=64 tile MAC: acc += A[ar..ar+15][0:64] * B[br..br+15][0:64]^T  (hi/lo 3-combo)
__device__ __forceinline__ f32x4 mm64(
    const unsigned short* Ah, const unsigned short* Al,
    const unsigned short* Bh, const unsigned short* Bl,
    int ar, int br, int lrow, int lkb, f32x4 acc)
{
    const int ra = ar + lrow, rb = br + lrow;
    bf16x8 ah0 = LD8(Ah, ra, lkb), ah1 = LD8(Ah, ra, lkb+64);
    bf16x8 al0 = LD8(Al, ra, lkb), al1 = LD8(Al, ra, lkb+64);
    bf16x8 bh0 = LD8(Bh, rb, lkb), bh1 = LD8(Bh, rb, lkb+64);
    bf16x8 bl0 = LD8(Bl, rb, lkb), bl1 = LD8(Bl, rb, lkb+64);
    acc = __builtin_amdgcn_mfma_f32_16x16x32_bf16(ah0, bh0, acc, 0,0,0);
    acc = __builtin_amdgcn_mfma_f32_16x16x32_bf16(ah1, bh1, acc, 0,0,0);
    acc = __builtin_amdgcn_mfma_f32_16x16x32_bf16(ah0, bl0, acc, 0,0,0);
    acc = __builtin_amdgcn_mfma_f32_16x16x32_bf16(ah1, bl1, acc, 0,0,0);
    acc = __builtin_amdgcn_mfma_f32_16x16x32_bf16(al0, bh0, acc, 0,0,0);
    acc = __builtin_amdgcn_mfma_f32_16x16x32_bf16(al1, bh1, acc, 0,0,0);
    return acc;
}

// =================== K1: MFMA bf16-hi/lo fused MLP, 1024 threads / 16 waves ===================
__global__ __launch_bounds__(1024) void k1_fused(
    const float* __restrict__ x, const float* __restrict__ y,
    const float* __restrict__ w11_1, const float* __restrict__ b11_1,
    const float* __restrict__ w11_2, const float* __restrict__ b11_2,
    const float* __restrict__ w12_1, const float* __restrict__ b12_1,
    const float* __restrict__ w12_2, const float* __restrict__ b12_2,
    float* __restrict__ out_x, float* __restrict__ out_y,
    float* __restrict__ mean_part)
{
    const int b = blockIdx.x >> 2, tile = blockIdx.x & 3;
    const int t = threadIdx.x;
    const int lane = t & 63, wv = t >> 6;          // wv 0..15
    const int lrow = lane & 15;
    const int lkb  = (lane >> 4) * 16;
    const int row0g = b*NS + tile*64;

    __shared__ unsigned short XYh[9216], XYl[9216];   // 128 rows
    __shared__ unsigned short W1h[4608], W1l[4608];   // 64 rows
    __shared__ unsigned short W2h[4608], W2l[4608];
    __shared__ unsigned short Hh [9216], Hl [9216];
    __shared__ unsigned short Oh [9216], Ol [9216];
    __shared__ float msum[16*68];

    // ---- P0: stage XY + W1^T + W2^T ----
    #pragma unroll
    for (int u=0;u<2;u++){
        int id = t + 1024*u;                // 2048 float4
        int r = id>>4, c0 = (id&15)*4;
        const float* src = (r < 64) ? (x + ((size_t)(row0g + r))*ND)
                                    : (y + ((size_t)(row0g + r - 64))*ND);
        float4 v = *(const float4*)(src + c0);
        sw2x2(XYh, XYl, r*72 + c0,   v.x, v.y);
        sw2x2(XYh, XYl, r*72 + c0+2, v.z, v.w);
    }
    if (t < 512){
        int rp = t>>4, c0 = (t&15)*4;       // 512 row-pair jobs
        float4 a0 = *(const float4*)(w11_1 + (size_t)(2*rp  )*64 + c0);
        float4 a1 = *(const float4*)(w11_1 + (size_t)(2*rp+1)*64 + c0);
        float4 b0 = *(const float4*)(w11_2 + (size_t)(2*rp  )*64 + c0);
        float4 b1 = *(const float4*)(w11_2 + (size_t)(2*rp+1)*64 + c0);
        #pragma unroll
        for (int i2=0;i2<4;i2++){
            sw2x2(W1h, W1l, (c0+i2)*72 + 2*rp, F4E(a0,i2), F4E(a1,i2));
            sw2x2(W2h, W2l, (c0+i2)*72 + 2*rp, F4E(b0,i2), F4E(b1,i2));
        }
    }
    __syncthreads();

    // ---- P1: G1  H = relu(XY @ W1 + b1): wave w -> (row-tile w>>1, col-tiles 2*(w&1)+q) ----
    const int rtA = wv >> 1, cpA = wv & 1;
    {
        const int ar = 16*rtA;
        #pragma unroll
        for (int q=0; q<2; q++){
            const int jt = 2*cpA + q;
            float bb = b11_1[jt*16 + lrow];
            f32x4 acc = {bb,bb,bb,bb};
            acc = mm64(XYh, XYl, W1h, W1l, ar, jt*16, lrow, lkb, acc);
            #pragma unroll
            for (int e=0;e<4;e++){
                int row = ar + (lane>>4)*4 + e;
                int col = jt*16 + lrow;
                sw2(Hh, Hl, row*72 + col, fmaxf(acc[e], 0.f));
            }
        }
    }
    __syncthreads();

    // ---- P2: stage w12_1^T half0 -> XY region; G2  O = H @ W2 + b2 ----
    {
        int krp = t>>5, c0 = (t&31)*4;      // 1024 row-pair jobs
        float4 v0 = *(const float4*)(w12_1 + (size_t)(2*krp  )*NH + c0);
        float4 v1 = *(const float4*)(w12_1 + (size_t)(2*krp+1)*NH + c0);
        #pragma unroll
        for (int i2=0;i2<4;i2++)
            sw2x2(XYh, XYl, (c0+i2)*72 + 2*krp, F4E(v0,i2), F4E(v1,i2));
    }
    {
        const int ar = 16*rtA;
        #pragma unroll
        for (int q=0; q<2; q++){
            const int jt = 2*cpA + q;
            float bb = b11_2[jt*16 + lrow];
            f32x4 acc = {bb,bb,bb,bb};
            acc = mm64(Hh, Hl, W2h, W2l, ar, jt*16, lrow, lkb, acc);
            #pragma unroll
            for (int e=0;e<4;e++){
                int row = ar + (lane>>4)*4 + e;
                int col = jt*16 + lrow;
                float v = acc[e];
                sw2(Oh, Ol, row*72 + col, v);
                float* dst = (row < 64) ? out_x : out_y;
                dst[((size_t)(row0g + (row & 63)))*NH2 + col] = v;
            }
        }
    }
    __syncthreads();

    // ---- P3: G3 pass0: wave w -> (rt=w&3, jt=2*(w>>2)+q) ----
    const int rt = wv & 3, cq = wv >> 2;    // cq 0..3
    f32x4 acc3[2];
    #pragma unroll
    for (int q=0; q<2; q++){
        const int jt = 2*cq + q;
        float bb = b12_1[jt*16 + lrow];
        f32x4 v = {bb,bb,bb,bb};
        acc3[q] = v;
        acc3[q] = mm64(Oh, Ol, XYh, XYl, 16*rt, 16*jt, lrow, lkb, acc3[q]);
    }
    __syncthreads();

    // ---- P4: stage w12_1^T half1 -> XY; w12_2^T halves -> W2(h0)/W1(h1) ----
    {
        int krp = t>>5, c0 = (t&31)*4;
        float4 v0 = *(const float4*)(w12_1 + (size_t)(64+2*krp  )*NH + c0);
        float4 v1 = *(const float4*)(w12_1 + (size_t)(64+2*krp+1)*NH + c0);
        #pragma unroll
        for (int i2=0;i2<4;i2++)
            sw2x2(XYh, XYl, (c0+i2)*72 + 2*krp, F4E(v0,i2), F4E(v1,i2));
    }
    if (t < 512){
        int krp = t>>4, c0 = (t&15)*4;      // 512 row-pair jobs
        float4 h0a = *(const float4*)(w12_2 + (size_t)(2*krp  )*NH2 + c0);
        float4 h0b = *(const float4*)(w12_2 + (size_t)(2*krp+1)*NH2 + c0);
        float4 h1a = *(const float4*)(w12_2 + (size_t)(64+2*krp  )*NH2 + c0);
        float4 h1b = *(const float4*)(w12_2 + (size_t)(64+2*krp+1)*NH2 + c0);
        #pragma unroll
        for (int i2=0;i2<4;i2++){
            sw2x2(W2h, W2l, (c0+i2)*72 + 2*krp, F4E(h0a,i2), F4E(h0b,i2));
            sw2x2(W1h, W1l, (c0+i2)*72 + 2*krp, F4E(h1a,i2), F4E(h1b,i2));
        }
    }
    __syncthreads();

    // ---- P5: G3 pass1 + epi -> H1 into H region ----
    #pragma unroll
    for (int q=0; q<2; q++)
        acc3[q] = mm64(Oh, Ol, XYh, XYl, 64 + 16*rt, 16*(2*cq+q), lrow, lkb, acc3[q]);
    #pragma unroll
    for (int q=0; q<2; q++){
        const int jt = 2*cq + q;
        #pragma unroll
        for (int e=0;e<4;e++){
            int row = 16*rt + (lane>>4)*4 + e;        // sample 0..63
            int col = 16*jt + lrow;                   // 0..127
            float v = fmaxf(acc3[q][e], 0.f);
            int idx = (col < 64) ? (row*72 + col) : ((64+row)*72 + (col-64));
            sw2(Hh, Hl, idx, v);
        }
    }
    __syncthreads();

    // ---- P6: G4: wave w -> (rt=w&3, jt=w>>2) ----
    {
        const int jc = cq;                  // 0..3
        float bb = b12_2[jc*16 + lrow];
        f32x4 acc2 = {bb,bb,bb,bb};
        acc2 = mm64(Hh, Hl, W2h, W2l, 16*rt,      16*jc, lrow, lkb, acc2);
        acc2 = mm64(Hh, Hl, W1h, W1l, 64 + 16*rt, 16*jc, lrow, lkb, acc2);
        float s = fmaxf(acc2[0],0.f) + fmaxf(acc2[1],0.f)
                + fmaxf(acc2[2],0.f) + fmaxf(acc2[3],0.f);
        s += __shfl_down(s, 32);
        s += __shfl_down(s, 16);
        if (lane < 16) msum[wv*68 + jc*16 + lane] = s;
    }
    __syncthreads();
    // column t (0..63): col-tile jt=t>>4 written by waves w = jt*4 + r (r = their rt)
    if (t < 64){
        const int w0 = (t>>4)*4;
        float ss = msum[(w0+0)*68 + t] + msum[(w0+1)*68 + t]
                 + msum[(w0+2)*68 + t] + msum[(w0+3)*68 + t];
        mean_part[((size_t)(b*4+tile))*64 + t] = ss;
    }
}

// =================== K2AB: center-first MFMA gram + Neumann/Horner solve (256 thr) ===================
__global__ __launch_bounds__(256) void k2ab(
    const float* __restrict__ fx, const float* __restrict__ fy,
    const float* __restrict__ x, const float* __restrict__ y,
    float* __restrict__ wbuf)
{
    const int bs = blockIdx.x;
    const int side = bs & 1, b = bs >> 1;
    const float* feat = side ? fy : fx;
    const float* targ = side ? x : y;
    float* wb = wbuf + (size_t)bs*WSTRIDE;
    const int t = threadIdx.x;
    const int lane = t & 63, wv = t >> 6;
    const int lrow = lane & 15;
    const int lkb  = (lane >> 4) * 16;
    const float inv256 = 1.0f/256.0f;

    __shared__ float Wf[64*68];
    __shared__ float Rf[64*68];
    __shared__ unsigned short Zh[4608], Zl[4608], Th[4608], Tl[4608];
    __shared__ unsigned short Eh[4608], El[4608];
    __shared__ unsigned short Wth[2][4608], Wtl[2][4608];
    __shared__ float cspA[16*68], cspB[16*68];
    __shared__ float szs[64], sts[64];
    __shared__ float sc[8], red4[4];

    // ---- Phase A: raw col sums of Z,T and sum T^2 ----
    {
        float szp0=0.f,szp1=0.f,szp2=0.f,szp3=0.f;
        float stp0=0.f,stp1=0.f,stp2=0.f,stp3=0.f;
        float tsq=0.f;
        for (int c=0;c<4;c++){
            #pragma unroll
            for (int u=0;u<4;u++){
                int id = t + 256*u;
                int r = id>>4, c0 = (id&15)*4;
                float4 v = *(const float4*)(feat + ((size_t)(b*NS + c*64 + r))*NH2 + c0);
                float4 w = *(const float4*)(targ + ((size_t)(b*NS + c*64 + r))*ND + c0);
                szp0+=v.x; szp1+=v.y; szp2+=v.z; szp3+=v.w;
                stp0+=w.x; stp1+=w.y; stp2+=w.z; stp3+=w.w;
                tsq += w.x*w.x + w.y*w.y + w.z*w.z + w.w*w.w;
            }
        }
        const int g2 = t>>4, c0 = (t&15)*4;
        cspA[g2*68 + c0+0] = szp0; cspA[g2*68 + c0+1] = szp1;
        cspA[g2*68 + c0+2] = szp2; cspA[g2*68 + c0+3] = szp3;
        cspB[g2*68 + c0+0] = stp0; cspB[g2*68 + c0+1] = stp1;
        cspB[g2*68 + c0+2] = stp2; cspB[g2*68 + c0+3] = stp3;
        float tq = tsq;
        #pragma unroll
        for (int off=32; off; off>>=1) tq += __shfl_down(tq, off);
        if (lane==0) red4[wv] = tq;
    }
    __syncthreads();
    if (t < 64){
        float sa=0.f, sb=0.f;
        #pragma unroll
        for (int g2=0; g2<16; g2++){ sa += cspA[g2*68+t]; sb += cspB[g2*68+t]; }
        szs[t] = sa; sts[t] = sb;
        float s2 = sa*sa;
        #pragma unroll
        for (int off=32; off; off>>=1) s2 += __shfl_down(s2, off);
        if (t==0) sc[2] = s2;
    }
    if (t==0) sc[1] = red4[0]+red4[1]+red4[2]+red4[3];
    __syncthreads();

    // ---- Phase B: gram of CENTERED Z, Rc = Zc^T T ----
    f32x4 accA[4], accR[4];
    #pragma unroll
    for (int jt=0;jt<4;jt++){
        f32x4 z = {0.f,0.f,0.f,0.f};
        accA[jt]=z; accR[jt]=z;
    }
    for (int c=0;c<4;c++){
        if (c) __syncthreads();
        #pragma unroll
        for (int u=0;u<4;u++){
            int id = t + 256*u;
            int r = id>>4, c0 = (id&15)*4;
            float4 v = *(const float4*)(feat + ((size_t)(b*NS + c*64 + r))*NH2 + c0);
            float4 w = *(const float4*)(targ + ((size_t)(b*NS + c*64 + r))*ND + c0);
            v.x -= szs[c0+0]*inv256; v.y -= szs[c0+1]*inv256;
            v.z -= szs[c0+2]*inv256; v.w -= szs[c0+3]*inv256;
            sw2(Zh,Zl,(c0+0)*72+r, v.x); sw2(Zh,Zl,(c0+1)*72+r, v.y);
            sw2(Zh,Zl,(c0+2)*72+r, v.z); sw2(Zh,Zl,(c0+3)*72+r, v.w);
            sw2(Th,Tl,(c0+0)*72+r, w.x); sw2(Th,Tl,(c0+1)*72+r, w.y);
            sw2(Th,Tl,(c0+2)*72+r, w.z); sw2(Th,Tl,(c0+3)*72+r, w.w);
        }
        __syncthreads();
        #pragma unroll
        for (int jt=0;jt<4;jt++){
            accA[jt] = mm64(Zh,Zl,Zh,Zl, 16*wv, 16*jt, lrow, lkb, accA[jt]);
            accR[jt] = mm64(Zh,Zl,Th,Tl, 16*wv, 16*jt, lrow, lkb, accR[jt]);
        }
    }
    {
        const int gi0 = 16*wv + (lane>>4)*4;
        #pragma unroll
        for (int jt=0;jt<4;jt++){
            #pragma unroll
            for (int e=0;e<4;e++){
                Wf[(gi0+e)*68 + 16*jt + lrow] = accA[jt][e];
                Rf[(gi0+e)*68 + 16*jt + lrow] = accR[jt][e];
            }
        }
    }
    __syncthreads();
    if (t<64){
        float dg = Wf[t*68+t];
        #pragma unroll
        for (int off=32; off; off>>=1) dg += __shfl_down(dg, off);
        if (t==0){
            float zn2 = dg + sc[2]*inv256;
            sc[0] = 1.0f/sqrtf(zn2);
            sc[1] = 1.0f/sqrtf(sc[1]);
        }
    }
    __syncthreads();
    const float zinv = sc[0], tinv = sc[1];
    const float z2 = zinv*zinv, zt = zinv*tinv;
    const float i23 = 2.0f/3.0f, i13 = 1.0f/3.0f;
    const int i = t>>2, qd = t&3;
    {
        #pragma unroll
        for (int q=0;q<4;q++){
            const int j = qd*16 + q*4;
            float4 a4 = *(const float4*)(Wf + i*68 + j);
            float e0 = i23*z2*a4.x - ((i==j  ) ? i13 : 0.f);
            float e1 = i23*z2*a4.y - ((i==j+1) ? i13 : 0.f);
            float e2 = i23*z2*a4.z - ((i==j+2) ? i13 : 0.f);
            float e3 = i23*z2*a4.w - ((i==j+3) ? i13 : 0.f);
            sw2x2(Eh, El, i*72 + j,   e0, e1);
            sw2x2(Eh, El, i*72 + j+2, e2, e3);
            float4 rv = *(float4*)(Rf + i*68 + j);
            float r0 = i23*zt*rv.x;
            float r1 = i23*zt*rv.y;
            float r2 = i23*zt*rv.z;
            float r3 = i23*zt*rv.w;
            *(float4*)(Rf + i*68 + j) = make_float4(r0,r1,r2,r3);
            sw2(Wth[0], Wtl[0], (j  )*72 + i, r0);
            sw2(Wth[0], Wtl[0], (j+1)*72 + i, r1);
            sw2(Wth[0], Wtl[0], (j+2)*72 + i, r2);
            sw2(Wth[0], Wtl[0], (j+3)*72 + i, r3);
        }
    }
    __syncthreads();

    int cur = 0;
    for (int n=0; n<12; n++){
        f32x4 acc[4];
        #pragma unroll
        for (int jt=0; jt<4; jt++){
            f32x4 zz = {0.f,0.f,0.f,0.f};
            acc[jt] = mm64(Eh, El, Wth[cur], Wtl[cur], 16*wv, jt*16, lrow, lkb, zz);
        }
        const int gi0 = 16*wv + (lane>>4)*4;
        #pragma unroll
        for (int jt=0; jt<4; jt++){
            const int gj = jt*16 + lrow;
            float w0 = Rf[(gi0  )*68 + gj] - acc[jt][0];
            float w1 = Rf[(gi0+1)*68 + gj] - acc[jt][1];
            float w2 = Rf[(gi0+2)*68 + gj] - acc[jt][2];
            float w3 = Rf[(gi0+3)*68 + gj] - acc[jt][3];
            sw2x2(Wth[cur^1], Wtl[cur^1], gj*72 + gi0,   w0, w1);
            sw2x2(Wth[cur^1], Wtl[cur^1], gj*72 + gi0+2, w2, w3);
            if (n == 11){
                Wf[(gi0  )*68 + gj] = w0;  wb[(gi0  )*64 + gj] = w0;
                Wf[(gi0+1)*68 + gj] = w1;  wb[(gi0+1)*64 + gj] = w1;
                Wf[(gi0+2)*68 + gj] = w2;  wb[(gi0+2)*64 + gj] = w2;
                Wf[(gi0+3)*68 + gj] = w3;  wb[(gi0+3)*64 + gj] = w3;
            }
        }
        cur ^= 1;
        __syncthreads();
    }

    if (t < 64){
        float s = 0.f;
        for (int i2=0; i2<64; i2++) s += szs[i2]*Wf[i2*68 + t];
        wb[4096+t] = (tinv*sts[t] - zinv*s) * inv256;
    }
    if (t==0){ wb[4160] = zinv; wb[4161] = tinv; }
}

// =================== KRG: fused residual + Renyi Gram, 1024 threads / 16 waves ===================
__global__ __launch_bounds__(1024) void kRG(
    const float* __restrict__ fx, const float* __restrict__ fy,
    const float* __restrict__ x, const float* __restrict__ y,
    const float* __restrict__ wbuf,
    float* __restrict__ part3, float* __restrict__ dout)
{
    const int blk = blockIdx.x;
    const int jh = blk & 1;
    const int b = (blk >> 1) & (NB-1);
    const int side = (blk >> 1) >> 6;
    const float* feat = side ? fy : fx;
    const float* targ = side ? x : y;
    const float* bmat = side ? y : x;
    const float* wb = wbuf + (size_t)(b*2+side)*WSTRIDE;
    const int t = threadIdx.x;
    const int lane = t & 63, wv = t >> 6;          // wv 0..15
    const int lrow = lane & 15, lkb = (lane>>4)*16;

    __shared__ unsigned short resA[256*72];
    __shared__ unsigned short tgB [256*72];
    __shared__ unsigned short Zh[2*4608], Zl[2*4608];
    __shared__ unsigned short Wth[4608], Wtl[4608];
    __shared__ float c0s[64];
    __shared__ float nAs[256], nBs[256];
    __shared__ float red[16][3];
    __shared__ float lred[16];

    {
        int k = t>>4, c0 = (t&15)*4;         // 1024 float4 over W rows k
        float4 v = *(const float4*)(wb + (size_t)k*64 + c0);
        sw2(Wth, Wtl, (c0+0)*72 + k, v.x);
        sw2(Wth, Wtl, (c0+1)*72 + k, v.y);
        sw2(Wth, Wtl, (c0+2)*72 + k, v.z);
        sw2(Wth, Wtl, (c0+3)*72 + k, v.w);
    }
    if (t<64) c0s[t] = wb[4096+t];
    const float zinv = wb[4160], tinv = wb[4161];
    #pragma unroll
    for (int u=0;u<4;u++){
        int id = t + 1024*u;                 // 4096 float4
        int r = id>>4, c0 = (id&15)*4;
        float4 v = *(const float4*)(bmat + ((size_t)(b*NS+r))*ND + c0);
        ushort4 h;
        h.x=f2bf(v.x); h.y=f2bf(v.y); h.z=f2bf(v.z); h.w=f2bf(v.w);
        *(ushort4*)(tgB + r*72 + c0) = h;
    }
    {
        int r = t>>4, c0 = (t&15)*4;         // 1024 float4, chunk 0
        float4 v = *(const float4*)(feat + ((size_t)(b*NS + r))*NH2 + c0);
        sw2x2(Zh, Zl, r*72+c0,   v.x, v.y);
        sw2x2(Zh, Zl, r*72+c0+2, v.z, v.w);
    }
    __syncthreads();

    // ---- residual: 4 chunks of 64 rows; wave w -> (rt=w&3, ct=w>>2), 1 tile each ----
    const int rt = wv & 3, ct = wv >> 2;     // ct 0..3
    float lacc = 0.f;
    for (int c=0; c<4; c++){
        if (c < 3){
            unsigned short* zh = Zh + ((c+1)&1)*4608;
            unsigned short* zl = Zl + ((c+1)&1)*4608;
            int r = t>>4, c0 = (t&15)*4;
            float4 v = *(const float4*)(feat + ((size_t)(b*NS + (c+1)*64 + r))*NH2 + c0);
            sw2x2(zh, zl, r*72+c0,   v.x, v.y);
            sw2x2(zh, zl, r*72+c0+2, v.z, v.w);
        }
        const unsigned short* zh = Zh + (c&1)*4608;
        const unsigned short* zl = Zl + (c&1)*4608;
        f32x4 zz = {0.f,0.f,0.f,0.f};
        f32x4 acc = mm64(zh, zl, Wth, Wtl, 16*rt, 16*ct, lrow, lkb, zz);
        const int r0 = 16*rt + (lane>>4)*4;
        const int gj = 16*ct + lrow;
        const float cc = c0s[gj];
        #pragma unroll
        for (int e=0;e<4;e++){
            const int grow = c*64 + r0 + e;
            float qv = targ[((size_t)(b*NS+grow))*ND + gj];
            float rr = tinv*qv - zinv*acc[e] - cc;
            lacc += rr*rr;
            resA[grow*72 + gj] = f2bf(rr);
        }
        __syncthreads();
    }

    {
        float l = lacc;
        #pragma unroll
        for (int off=32; off; off>>=1) l += __shfl_down(l, off);
        if (lane==0) lred[wv] = l;
    }
    if (t < 256){
        float sa=0.f, sb=0.f;
        #pragma unroll
        for (int j8=0;j8<8;j8++){
            bf16x8 va = *(const bf16x8*)((const char*)resA + (size_t)t*144 + j8*16);
            bf16x8 vb = *(const bf16x8*)((const char*)tgB  + (size_t)t*144 + j8*16);
            #pragma unroll
            for (int e2=0;e2<8;e2++){
                float fa = bf2f((unsigned short)va[e2]);
                float fb = bf2f((unsigned short)vb[e2]);
                sa += fa*fa; sb += fb*fb;
            }
        }
        nAs[t] = sa; nBs[t] = sb;
    }
    __syncthreads();
    if (t==0 && jh==0){
        float ls = 0.f;
        #pragma unroll
        for (int w=0;w<16;w++) ls += lred[w];
        dout[(side?256:192)+b] = ls;
    }

    // ---- Gram + exp: wave w -> i-tile i0 = 16w ----
    const char* pA = (const char*)resA;
    const char* pB = (const char*)tgB;
    const f32x4 zero4 = {0.f, 0.f, 0.f, 0.f};
    const float CEXP = -2.8853900817779268f;

    float Sa=0.f, Sb=0.f, Sab=0.f;
    {
        const int i0 = wv*16;
        const int arow = i0 + lrow;
        bf16x8 aA0 = *(const bf16x8*)(pA + arow*144 + lkb);
        bf16x8 aA1 = *(const bf16x8*)(pA + arow*144 + lkb + 64);
        bf16x8 aB0 = *(const bf16x8*)(pB + arow*144 + lkb);
        bf16x8 aB1 = *(const bf16x8*)(pB + arow*144 + lkb + 64);
        float nAi[4], nBi[4];
        #pragma unroll
        for (int e=0;e<4;e++){
            int gi = i0 + (lane>>4)*4 + e;
            nAi[e] = nAs[gi]; nBi[e] = nBs[gi];
        }
        #pragma unroll
        for (int jt=0; jt<8; jt++){
            const int j0 = jh*128 + jt*16;
            const int brow = j0 + lrow;
            bf16x8 bA0 = *(const bf16x8*)(pA + brow*144 + lkb);
            bf16x8 bA1 = *(const bf16x8*)(pA + brow*144 + lkb + 64);
            bf16x8 bB0 = *(const bf16x8*)(pB + brow*144 + lkb);
            bf16x8 bB1 = *(const bf16x8*)(pB + brow*144 + lkb + 64);
            f32x4 cA = __builtin_amdgcn_mfma_f32_16x16x32_bf16(aA0, bA0, zero4, 0, 0, 0);
            cA = __builtin_amdgcn_mfma_f32_16x16x32_bf16(aA1, bA1, cA, 0, 0, 0);
            f32x4 cB = __builtin_amdgcn_mfma_f32_16x16x32_bf16(aB0, bB0, zero4, 0, 0, 0);
            cB = __builtin_amdgcn_mfma_f32_16x16x32_bf16(aB1, bB1, cB, 0, 0, 0);
            const int gj = j0 + lrow;
            const float nAj = nAs[gj], nBj = nBs[gj];
            #pragma unroll
            for (int e=0;e<4;e++){
                const int gi = i0 + (lane>>4)*4 + e;
                const float dda = (gi==gj) ? 0.f : (nAi[e] + nAj - 2.f*cA[e]);
                const float ddb = (gi==gj) ? 0.f : (nBi[e] + nBj - 2.f*cB[e]);
                const float ka2 = exp2f(CEXP*dda);
                const float kb2 = exp2f(CEXP*ddb);
                Sa += ka2; Sb += kb2; Sab += ka2*kb2;
            }
        }
    }
    #pragma unroll
    for (int off=32; off; off>>=1){
        Sa += __shfl_down(Sa,off); Sb += __shfl_down(Sb,off); Sab += __shfl_down(Sab,off);
    }
    if (lane==0){ red[wv][0]=Sa; red[wv][1]=Sb; red[wv][2]=Sab; }
    __syncthreads();
    if (t==0){
        float s0=0.f, s1=0.f, s2=0.f;
        #pragma unroll
        for (int w=0;w<16;w++){ s0 += red[w][0]; s1 += red[w][1]; s2 += red[w][2]; }
        float* o = part3 + (size_t)blk*3;
        o[0] = s0; o[1] = s1; o[2] = s2;
    }
}

// =================== K4 ===================
__global__ __launch_bounds__(64) void k4_final(
    const float* __restrict__ mean_part, const float* __restrict__ part3,
    const float* __restrict__ wc1, const float* __restrict__ bc1,
    const float* __restrict__ bn_gamma, const float* __restrict__ bn_beta,
    const float* __restrict__ w2, const float* __restrict__ b2,
    const float* __restrict__ wc2, const float* __restrict__ bc2,
    float* __restrict__ dout)
{
    const int t = threadIdx.x;
    __shared__ float ic[64][5];
    __shared__ float mu[5], iv[5];

    float o0 = bc1[0], o1 = bc1[1], o2 = bc1[2];
    for (int c=0;c<64;c++){
        float mv = mean_part[(t*4+0)*64+c] + mean_part[(t*4+1)*64+c]
                 + mean_part[(t*4+2)*64+c] + mean_part[(t*4+3)*64+c];
        mv *= (1.0f/256.0f);
        o0 += mv*wc1[c*3+0]; o1 += mv*wc1[c*3+1]; o2 += mv*wc1[c*3+2];
    }
    dout[t*3+0]=o0; dout[t*3+1]=o1; dout[t*3+2]=o2;
    {
        float m = fmaxf(o0,fmaxf(o1,o2));
        float e0=__expf(o0-m), e1=__expf(o1-m), e2=__expf(o2-m);
        float inv = 1.f/(e0+e1+e2);
        dout[640+t*3+0]=e0*inv; dout[640+t*3+1]=e1*inv; dout[640+t*3+2]=e2*inv;
    }
    float exy[2];
    #pragma unroll
    for (int side=0; side<2; side++){
        const float* pp = part3 + (size_t)((side*NB + t)*2)*3;
        float Sa = pp[0]+pp[3];
        float Sb = pp[1]+pp[4];
        float Sab= pp[2]+pp[5];
        float Hx  = 16.f - log2f(Sa);
        float Hy  = 16.f - log2f(Sb);
        float Hxy = 16.f - log2f(Sab);
        float mi = (Hx + Hy - Hxy) / fmaxf(Hx, Hy);
        dout[(side?384:320)+t] = mi;
        exy[side] = mi;
    }
    ic[t][0]=o0; ic[t][1]=o1; ic[t][2]=o2; ic[t][3]=exy[0]; ic[t][4]=exy[1];
    __syncthreads();
    if (t<5){
        float m=0.f;
        for (int bb=0;bb<64;bb++) m += ic[bb][t];
        m *= (1.f/64.f);
        float v=0.f;
        for (int bb=0;bb<64;bb++){ float d=ic[bb][t]-m; v+=d*d; }
        v *= (1.f/64.f);
        mu[t]=m; iv[t]=1.f/sqrtf(v+1e-5f);
    }
    __syncthreads();
    float vn[5];
    #pragma unroll
    for (int c=0;c<5;c++) vn[c] = (ic[t][c]-mu[c])*iv[c]*bn_gamma[c]+bn_beta[c];
    float q0=bc2[0], q1=bc2[1], q2=bc2[2];
    for (int j=0;j<64;j++){
        float hh = b2[j];
        #pragma unroll
        for (int c=0;c<5;c++) hh += vn[c]*w2[c*64+j];
        hh = fmaxf(hh,0.f);
        q0 += hh*wc2[j*3+0]; q1 += hh*wc2[j*3+1]; q2 += hh*wc2[j*3+2];
    }
    dout[448+t*3+0]=q0; dout[448+t*3+1]=q1; dout[448+t*3+2]=q2;
    float m = fmaxf(q0,fmaxf(q1,q2));
    float e0=__expf(q0-m), e1=__expf(q1-m), e2=__expf(q2-m);
    float inv=1.f/(e0+e1+e2);
    dout[832+t*3+0]=e0*inv; dout[832+t*3+1]=e1*inv; dout[832+t*3+2]=e2*inv;
}

extern "C" void kernel_launch(void* const* d_in, const int* in_sizes, int n_in,
                              void* d_out, int out_size, void* d_ws, size_t ws_size,
                              hipStream_t stream)
{
    const float* x     = (const float*)d_in[0];
    const float* y     = (const float*)d_in[1];
    const float* w11_1 = (const float*)d_in[2];
    const float* b11_1 = (const float*)d_in[3];
    const float* w11_2 = (const float*)d_in[4];
    const float* b11_2 = (const float*)d_in[5];
    const float* w12_1 = (const float*)d_in[6];
    const float* b12_1 = (const float*)d_in[7];
    const float* w12_2 = (const float*)d_in[8];
    const float* b12_2 = (const float*)d_in[9];
    const float* wc1   = (const float*)d_in[10];
    const float* bc1   = (const float*)d_in[11];
    const float* bn_g  = (const float*)d_in[12];
    const float* bn_b  = (const float*)d_in[13];
    const float* w2    = (const float*)d_in[14];
    const float* b2    = (const float*)d_in[15];
    const float* wc2   = (const float*)d_in[16];
    const float* bc2   = (const float*)d_in[17];

    float* ws   = (float*)d_ws;
    float* dout = (float*)d_out;
    float* out_x = ws;                           // 1,048,576 floats
    float* out_y = ws + 1048576;
    float* mean_part = ws + 2097152;             // 16384
    float* part3 = mean_part + 16384;            // 768 (alloc 3840)
    float* wbuf  = part3 + 3840;                 // 128*4224 = 540672

    hipLaunchKernelGGL(k1_fused, dim3(NB*4), dim3(1024), 0, stream,
        x,y,w11_1,b11_1,w11_2,b11_2,w12_1,b12_1,w12_2,b12_2,
        out_x,out_y,mean_part);
    hipLaunchKernelGGL(k2ab, dim3(2*NB), dim3(256), 0, stream,
        out_x,out_y,x,y,wbuf);
    hipLaunchKernelGGL(kRG, dim3(NB*2*2), dim3(1024), 0, stream,
        out_x,out_y,x,y,wbuf,part3,dout);
    hipLaunchKernelGGL(k4_final, dim3(1), dim3(64), 0, stream,
        mean_part,part3,wc1,bc1,bn_g,bn_b,w2,b2,wc2,bc2,dout);
}

// Round 15
// 75.082 us; speedup vs baseline: 1.3209x; 1.0230x over previous
//
#include <hip/hip_runtime.h>
#include <math.h>

#define NB 64
#define NS 256
#define ND 64
#define NH2 64
#define NH 128
#define WSTRIDE 4224

// d_out layout (floats):
// 0: out_c[64*3]; 192: rx[64]; 256: ry[64]; 320: ex[64]; 384: ey[64];
// 448: out_c_f[64*3]; 640: prob1[64*3]; 832: prob2[64*3]

#define F4E(v_, e_) ((e_)==0?(v_).x:((e_)==1?(v_).y:((e_)==2?(v_).z:(v_).w)))

typedef __attribute__((ext_vector_type(8))) short bf16x8;
typedef __attribute__((ext_vector_type(4))) float f32x4;

__device__ __forceinline__ unsigned short f2bf(float f){
    union { float f; unsigned int u; } v; v.f = f;
    unsigned int r = v.u + 0x7fffu + ((v.u >> 16) & 1u);
    return (unsigned short)(r >> 16);
}
__device__ __forceinline__ float bf2f(unsigned short h){
    union { unsigned int u; float f; } v; v.u = ((unsigned int)h) << 16;
    return v.f;
}
__device__ __forceinline__ void sw2(unsigned short* ph, unsigned short* pl, int idx, float f){
    unsigned short h = f2bf(f);
    ph[idx] = h;
    pl[idx] = f2bf(f - bf2f(h));
}
__device__ __forceinline__ void sw2x2(unsigned short* ph, unsigned short* pl, int idx, float f0, float f1){
    unsigned short h0 = f2bf(f0), h1 = f2bf(f1);
    ushort2 hh; hh.x = h0; hh.y = h1;
    *(ushort2*)(ph + idx) = hh;
    ushort2 ll; ll.x = f2bf(f0 - bf2f(h0)); ll.y = f2bf(f1 - bf2f(h1));
    *(ushort2*)(pl + idx) = ll;
}

#define LD8(P_, row_, kb_) (*(const bf16x8*)((const char*)(P_) + (size_t)(row_)*144 + (kb_)))

// K=64 tile MAC: acc += A[ar..ar+15][0:64] * B[br..br+15][0:64]^T  (hi/lo 3-combo)
__device__ __forceinline__ f32x4 mm64(
    const unsigned short* Ah, const unsigned short* Al,
    const unsigned short* Bh, const unsigned short* Bl,
    int ar, int br, int lrow, int lkb, f32x4 acc)
{
    const int ra = ar + lrow, rb = br + lrow;
    bf16x8 ah0 = LD8(Ah, ra, lkb), ah1 = LD8(Ah, ra, lkb+64);
    bf16x8 al0 = LD8(Al, ra, lkb), al1 = LD8(Al, ra, lkb+64);
    bf16x8 bh0 = LD8(Bh, rb, lkb), bh1 = LD8(Bh, rb, lkb+64);
    bf16x8 bl0 = LD8(Bl, rb, lkb), bl1 = LD8(Bl, rb, lkb+64);
    acc = __builtin_amdgcn_mfma_f32_16x16x32_bf16(ah0, bh0, acc, 0,0,0);
    acc = __builtin_amdgcn_mfma_f32_16x16x32_bf16(ah1, bh1, acc, 0,0,0);
    acc = __builtin_amdgcn_mfma_f32_16x16x32_bf16(ah0, bl0, acc, 0,0,0);
    acc = __builtin_amdgcn_mfma_f32_16x16x32_bf16(ah1, bl1, acc, 0,0,0);
    acc = __builtin_amdgcn_mfma_f32_16x16x32_bf16(al0, bh0, acc, 0,0,0);
    acc = __builtin_amdgcn_mfma_f32_16x16x32_bf16(al1, bh1, acc, 0,0,0);
    return acc;
}

// =================== K1: MFMA bf16-hi/lo fused MLP, 1024 threads / 16 waves ===================
__global__ __launch_bounds__(1024) void k1_fused(
    const float* __restrict__ x, const float* __restrict__ y,
    const float* __restrict__ w11_1, const float* __restrict__ b11_1,
    const float* __restrict__ w11_2, const float* __restrict__ b11_2,
    const float* __restrict__ w12_1, const float* __restrict__ b12_1,
    const float* __restrict__ w12_2, const float* __restrict__ b12_2,
    float* __restrict__ out_x, float* __restrict__ out_y,
    float* __restrict__ mean_part)
{
    const int b = blockIdx.x >> 2, tile = blockIdx.x & 3;
    const int t = threadIdx.x;
    const int lane = t & 63, wv = t >> 6;          // wv 0..15
    const int lrow = lane & 15;
    const int lkb  = (lane >> 4) * 16;
    const int row0g = b*NS + tile*64;

    __shared__ unsigned short XYh[9216], XYl[9216];   // 128 rows
    __shared__ unsigned short W1h[4608], W1l[4608];   // 64 rows
    __shared__ unsigned short W2h[4608], W2l[4608];
    __shared__ unsigned short Hh [9216], Hl [9216];
    __shared__ unsigned short Oh [9216], Ol [9216];
    __shared__ float msum[16*68];

    // ---- P0: stage XY + W1^T + W2^T ----
    #pragma unroll
    for (int u=0;u<2;u++){
        int id = t + 1024*u;                // 2048 float4
        int r = id>>4, c0 = (id&15)*4;
        const float* src = (r < 64) ? (x + ((size_t)(row0g + r))*ND)
                                    : (y + ((size_t)(row0g + r - 64))*ND);
        float4 v = *(const float4*)(src + c0);
        sw2x2(XYh, XYl, r*72 + c0,   v.x, v.y);
        sw2x2(XYh, XYl, r*72 + c0+2, v.z, v.w);
    }
    if (t < 512){
        int rp = t>>4, c0 = (t&15)*4;       // 512 row-pair jobs
        float4 a0 = *(const float4*)(w11_1 + (size_t)(2*rp  )*64 + c0);
        float4 a1 = *(const float4*)(w11_1 + (size_t)(2*rp+1)*64 + c0);
        float4 b0 = *(const float4*)(w11_2 + (size_t)(2*rp  )*64 + c0);
        float4 b1 = *(const float4*)(w11_2 + (size_t)(2*rp+1)*64 + c0);
        #pragma unroll
        for (int i2=0;i2<4;i2++){
            sw2x2(W1h, W1l, (c0+i2)*72 + 2*rp, F4E(a0,i2), F4E(a1,i2));
            sw2x2(W2h, W2l, (c0+i2)*72 + 2*rp, F4E(b0,i2), F4E(b1,i2));
        }
    }
    __syncthreads();

    // ---- P1: G1  H = relu(XY @ W1 + b1): wave w -> (row-tile w>>1, col-tiles 2*(w&1)+q) ----
    const int rtA = wv >> 1, cpA = wv & 1;
    {
        const int ar = 16*rtA;
        #pragma unroll
        for (int q=0; q<2; q++){
            const int jt = 2*cpA + q;
            float bb = b11_1[jt*16 + lrow];
            f32x4 acc = {bb,bb,bb,bb};
            acc = mm64(XYh, XYl, W1h, W1l, ar, jt*16, lrow, lkb, acc);
            #pragma unroll
            for (int e=0;e<4;e++){
                int row = ar + (lane>>4)*4 + e;
                int col = jt*16 + lrow;
                sw2(Hh, Hl, row*72 + col, fmaxf(acc[e], 0.f));
            }
        }
    }
    __syncthreads();

    // ---- P2: stage w12_1^T half0 -> XY region; G2  O = H @ W2 + b2 ----
    {
        int krp = t>>5, c0 = (t&31)*4;      // 1024 row-pair jobs
        float4 v0 = *(const float4*)(w12_1 + (size_t)(2*krp  )*NH + c0);
        float4 v1 = *(const float4*)(w12_1 + (size_t)(2*krp+1)*NH + c0);
        #pragma unroll
        for (int i2=0;i2<4;i2++)
            sw2x2(XYh, XYl, (c0+i2)*72 + 2*krp, F4E(v0,i2), F4E(v1,i2));
    }
    {
        const int ar = 16*rtA;
        #pragma unroll
        for (int q=0; q<2; q++){
            const int jt = 2*cpA + q;
            float bb = b11_2[jt*16 + lrow];
            f32x4 acc = {bb,bb,bb,bb};
            acc = mm64(Hh, Hl, W2h, W2l, ar, jt*16, lrow, lkb, acc);
            #pragma unroll
            for (int e=0;e<4;e++){
                int row = ar + (lane>>4)*4 + e;
                int col = jt*16 + lrow;
                float v = acc[e];
                sw2(Oh, Ol, row*72 + col, v);
                float* dst = (row < 64) ? out_x : out_y;
                dst[((size_t)(row0g + (row & 63)))*NH2 + col] = v;
            }
        }
    }
    __syncthreads();

    // ---- P3: G3 pass0: wave w -> (rt=w&3, jt=2*(w>>2)+q) ----
    const int rt = wv & 3, cq = wv >> 2;    // cq 0..3
    f32x4 acc3[2];
    #pragma unroll
    for (int q=0; q<2; q++){
        const int jt = 2*cq + q;
        float bb = b12_1[jt*16 + lrow];
        f32x4 v = {bb,bb,bb,bb};
        acc3[q] = v;
        acc3[q] = mm64(Oh, Ol, XYh, XYl, 16*rt, 16*jt, lrow, lkb, acc3[q]);
    }
    __syncthreads();

    // ---- P4: stage w12_1^T half1 -> XY; w12_2^T halves -> W2(h0)/W1(h1) ----
    {
        int krp = t>>5, c0 = (t&31)*4;
        float4 v0 = *(const float4*)(w12_1 + (size_t)(64+2*krp  )*NH + c0);
        float4 v1 = *(const float4*)(w12_1 + (size_t)(64+2*krp+1)*NH + c0);
        #pragma unroll
        for (int i2=0;i2<4;i2++)
            sw2x2(XYh, XYl, (c0+i2)*72 + 2*krp, F4E(v0,i2), F4E(v1,i2));
    }
    if (t < 512){
        int krp = t>>4, c0 = (t&15)*4;      // 512 row-pair jobs
        float4 h0a = *(const float4*)(w12_2 + (size_t)(2*krp  )*NH2 + c0);
        float4 h0b = *(const float4*)(w12_2 + (size_t)(2*krp+1)*NH2 + c0);
        float4 h1a = *(const float4*)(w12_2 + (size_t)(64+2*krp  )*NH2 + c0);
        float4 h1b = *(const float4*)(w12_2 + (size_t)(64+2*krp+1)*NH2 + c0);
        #pragma unroll
        for (int i2=0;i2<4;i2++){
            sw2x2(W2h, W2l, (c0+i2)*72 + 2*krp, F4E(h0a,i2), F4E(h0b,i2));
            sw2x2(W1h, W1l, (c0+i2)*72 + 2*krp, F4E(h1a,i2), F4E(h1b,i2));
        }
    }
    __syncthreads();

    // ---- P5: G3 pass1 + epi -> H1 into H region ----
    #pragma unroll
    for (int q=0; q<2; q++)
        acc3[q] = mm64(Oh, Ol, XYh, XYl, 64 + 16*rt, 16*(2*cq+q), lrow, lkb, acc3[q]);
    #pragma unroll
    for (int q=0; q<2; q++){
        const int jt = 2*cq + q;
        #pragma unroll
        for (int e=0;e<4;e++){
            int row = 16*rt + (lane>>4)*4 + e;        // sample 0..63
            int col = 16*jt + lrow;                   // 0..127
            float v = fmaxf(acc3[q][e], 0.f);
            int idx = (col < 64) ? (row*72 + col) : ((64+row)*72 + (col-64));
            sw2(Hh, Hl, idx, v);
        }
    }
    __syncthreads();

    // ---- P6: G4: wave w -> (rt=w&3, jt=w>>2) ----
    {
        const int jc = cq;                  // 0..3
        float bb = b12_2[jc*16 + lrow];
        f32x4 acc2 = {bb,bb,bb,bb};
        acc2 = mm64(Hh, Hl, W2h, W2l, 16*rt,      16*jc, lrow, lkb, acc2);
        acc2 = mm64(Hh, Hl, W1h, W1l, 64 + 16*rt, 16*jc, lrow, lkb, acc2);
        float s = fmaxf(acc2[0],0.f) + fmaxf(acc2[1],0.f)
                + fmaxf(acc2[2],0.f) + fmaxf(acc2[3],0.f);
        s += __shfl_down(s, 32);
        s += __shfl_down(s, 16);
        if (lane < 16) msum[wv*68 + jc*16 + lane] = s;
    }
    __syncthreads();
    if (t < 64){
        const int w0 = (t>>4)*4;
        float ss = msum[(w0+0)*68 + t] + msum[(w0+1)*68 + t]
                 + msum[(w0+2)*68 + t] + msum[(w0+3)*68 + t];
        mean_part[((size_t)(b*4+tile))*64 + t] = ss;
    }
}

// =================== K2AB: center-first MFMA gram + Neumann/Horner, 512 thr / 8 waves ===================
__global__ __launch_bounds__(512) void k2ab(
    const float* __restrict__ fx, const float* __restrict__ fy,
    const float* __restrict__ x, const float* __restrict__ y,
    float* __restrict__ wbuf)
{
    const int bs = blockIdx.x;
    const int side = bs & 1, b = bs >> 1;
    const float* feat = side ? fy : fx;
    const float* targ = side ? x : y;
    float* wb = wbuf + (size_t)bs*WSTRIDE;
    const int t = threadIdx.x;
    const int lane = t & 63, wv = t >> 6;          // wv 0..7
    const int lrow = lane & 15;
    const int lkb  = (lane >> 4) * 16;
    const float inv256 = 1.0f/256.0f;

    __shared__ float Wf[64*68];
    __shared__ float Rf[64*68];
    __shared__ unsigned short Zh[4608], Zl[4608], Th[4608], Tl[4608];
    __shared__ unsigned short Eh[4608], El[4608];
    __shared__ unsigned short Wth[2][4608], Wtl[2][4608];
    __shared__ float cspA[32*68], cspB[32*68];
    __shared__ float szs[64], sts[64];
    __shared__ float sc[8], red8[8];

    // ---- Phase A: raw col sums of Z,T and sum T^2 ----
    {
        float szp0=0.f,szp1=0.f,szp2=0.f,szp3=0.f;
        float stp0=0.f,stp1=0.f,stp2=0.f,stp3=0.f;
        float tsq=0.f;
        for (int c=0;c<4;c++){
            #pragma unroll
            for (int u=0;u<2;u++){
                int id = t + 512*u;
                int r = id>>4, c0 = (id&15)*4;
                float4 v = *(const float4*)(feat + ((size_t)(b*NS + c*64 + r))*NH2 + c0);
                float4 w = *(const float4*)(targ + ((size_t)(b*NS + c*64 + r))*ND + c0);
                szp0+=v.x; szp1+=v.y; szp2+=v.z; szp3+=v.w;
                stp0+=w.x; stp1+=w.y; stp2+=w.z; stp3+=w.w;
                tsq += w.x*w.x + w.y*w.y + w.z*w.z + w.w*w.w;
            }
        }
        const int g2 = t>>4, c0 = (t&15)*4;        // g2 0..31
        cspA[g2*68 + c0+0] = szp0; cspA[g2*68 + c0+1] = szp1;
        cspA[g2*68 + c0+2] = szp2; cspA[g2*68 + c0+3] = szp3;
        cspB[g2*68 + c0+0] = stp0; cspB[g2*68 + c0+1] = stp1;
        cspB[g2*68 + c0+2] = stp2; cspB[g2*68 + c0+3] = stp3;
        float tq = tsq;
        #pragma unroll
        for (int off=32; off; off>>=1) tq += __shfl_down(tq, off);
        if (lane==0) red8[wv] = tq;
    }
    __syncthreads();
    if (t < 64){
        float sa=0.f, sb=0.f;
        #pragma unroll
        for (int g2=0; g2<32; g2++){ sa += cspA[g2*68+t]; sb += cspB[g2*68+t]; }
        szs[t] = sa; sts[t] = sb;
        float s2 = sa*sa;
        #pragma unroll
        for (int off=32; off; off>>=1) s2 += __shfl_down(s2, off);
        if (t==0) sc[2] = s2;
    }
    if (t==0){
        float tn2 = 0.f;
        #pragma unroll
        for (int w=0;w<8;w++) tn2 += red8[w];
        sc[1] = tn2;
    }
    __syncthreads();

    // ---- Phase B: gram of CENTERED Z, Rc = Zc^T T ----
    // wave w -> i-tile (w&3), j-tiles 2*(w>>2)+q (q<2)
    const int git = wv & 3, gjp = wv >> 2;
    f32x4 accA[2], accR[2];
    #pragma unroll
    for (int q=0;q<2;q++){
        f32x4 z = {0.f,0.f,0.f,0.f};
        accA[q]=z; accR[q]=z;
    }
    for (int c=0;c<4;c++){
        if (c) __syncthreads();
        #pragma unroll
        for (int u=0;u<2;u++){
            int id = t + 512*u;
            int r = id>>4, c0 = (id&15)*4;
            float4 v = *(const float4*)(feat + ((size_t)(b*NS + c*64 + r))*NH2 + c0);
            float4 w = *(const float4*)(targ + ((size_t)(b*NS + c*64 + r))*ND + c0);
            v.x -= szs[c0+0]*inv256; v.y -= szs[c0+1]*inv256;
            v.z -= szs[c0+2]*inv256; v.w -= szs[c0+3]*inv256;
            sw2(Zh,Zl,(c0+0)*72+r, v.x); sw2(Zh,Zl,(c0+1)*72+r, v.y);
            sw2(Zh,Zl,(c0+2)*72+r, v.z); sw2(Zh,Zl,(c0+3)*72+r, v.w);
            sw2(Th,Tl,(c0+0)*72+r, w.x); sw2(Th,Tl,(c0+1)*72+r, w.y);
            sw2(Th,Tl,(c0+2)*72+r, w.z); sw2(Th,Tl,(c0+3)*72+r, w.w);
        }
        __syncthreads();
        #pragma unroll
        for (int q=0;q<2;q++){
            const int jt = 2*gjp + q;
            accA[q] = mm64(Zh,Zl,Zh,Zl, 16*git, 16*jt, lrow, lkb, accA[q]);
            accR[q] = mm64(Zh,Zl,Th,Tl, 16*git, 16*jt, lrow, lkb, accR[q]);
        }
    }
    {
        const int gi0 = 16*git + (lane>>4)*4;
        #pragma unroll
        for (int q=0;q<2;q++){
            const int jt = 2*gjp + q;
            #pragma unroll
            for (int e=0;e<4;e++){
                Wf[(gi0+e)*68 + 16*jt + lrow] = accA[q][e];
                Rf[(gi0+e)*68 + 16*jt + lrow] = accR[q][e];
            }
        }
    }
    __syncthreads();
    if (t<64){
        float dg = Wf[t*68+t];
        #pragma unroll
        for (int off=32; off; off>>=1) dg += __shfl_down(dg, off);
        if (t==0){
            float zn2 = dg + sc[2]*inv256;
            sc[0] = 1.0f/sqrtf(zn2);
            sc[1] = 1.0f/sqrtf(sc[1]);
        }
    }
    __syncthreads();
    const float zinv = sc[0], tinv = sc[1];
    const float z2 = zinv*zinv, zt = zinv*tinv;
    const float i23 = 2.0f/3.0f, i13 = 1.0f/3.0f;
    // E/R'' prep: 8 threads per row, 8 cols each
    {
        const int i = t>>3, qd = t&7;
        #pragma unroll
        for (int q=0;q<2;q++){
            const int j = qd*8 + q*4;
            float4 a4 = *(const float4*)(Wf + i*68 + j);
            float e0 = i23*z2*a4.x - ((i==j  ) ? i13 : 0.f);
            float e1 = i23*z2*a4.y - ((i==j+1) ? i13 : 0.f);
            float e2 = i23*z2*a4.z - ((i==j+2) ? i13 : 0.f);
            float e3 = i23*z2*a4.w - ((i==j+3) ? i13 : 0.f);
            sw2x2(Eh, El, i*72 + j,   e0, e1);
            sw2x2(Eh, El, i*72 + j+2, e2, e3);
            float4 rv = *(float4*)(Rf + i*68 + j);
            float r0 = i23*zt*rv.x;
            float r1 = i23*zt*rv.y;
            float r2 = i23*zt*rv.z;
            float r3 = i23*zt*rv.w;
            *(float4*)(Rf + i*68 + j) = make_float4(r0,r1,r2,r3);
            sw2(Wth[0], Wtl[0], (j  )*72 + i, r0);
            sw2(Wth[0], Wtl[0], (j+1)*72 + i, r1);
            sw2(Wth[0], Wtl[0], (j+2)*72 + i, r2);
            sw2(Wth[0], Wtl[0], (j+3)*72 + i, r3);
        }
    }
    __syncthreads();

    // Horner: W <- R'' - E*W  (12 iterations); wave w -> i-tile w&3, j-tiles 2*(w>>2)+q
    int cur = 0;
    for (int n=0; n<12; n++){
        f32x4 acc[2];
        #pragma unroll
        for (int q=0; q<2; q++){
            f32x4 zz = {0.f,0.f,0.f,0.f};
            acc[q] = mm64(Eh, El, Wth[cur], Wtl[cur], 16*git, 16*(2*gjp+q), lrow, lkb, zz);
        }
        const int gi0 = 16*git + (lane>>4)*4;
        #pragma unroll
        for (int q=0; q<2; q++){
            const int gj = 16*(2*gjp+q) + lrow;
            float w0 = Rf[(gi0  )*68 + gj] - acc[q][0];
            float w1 = Rf[(gi0+1)*68 + gj] - acc[q][1];
            float w2 = Rf[(gi0+2)*68 + gj] - acc[q][2];
            float w3 = Rf[(gi0+3)*68 + gj] - acc[q][3];
            sw2x2(Wth[cur^1], Wtl[cur^1], gj*72 + gi0,   w0, w1);
            sw2x2(Wth[cur^1], Wtl[cur^1], gj*72 + gi0+2, w2, w3);
            if (n == 11){
                Wf[(gi0  )*68 + gj] = w0;  wb[(gi0  )*64 + gj] = w0;
                Wf[(gi0+1)*68 + gj] = w1;  wb[(gi0+1)*64 + gj] = w1;
                Wf[(gi0+2)*68 + gj] = w2;  wb[(gi0+2)*64 + gj] = w2;
                Wf[(gi0+3)*68 + gj] = w3;  wb[(gi0+3)*64 + gj] = w3;
            }
        }
        cur ^= 1;
        __syncthreads();
    }

    if (t < 64){
        float s = 0.f;
        for (int i2=0; i2<64; i2++) s += szs[i2]*Wf[i2*68 + t];
        wb[4096+t] = (tinv*sts[t] - zinv*s) * inv256;
    }
    if (t==0){ wb[4160] = zinv; wb[4161] = tinv; }
}

// =================== KRG: fused residual + Renyi Gram, 1024 threads / 16 waves ===================
__global__ __launch_bounds__(1024) void kRG(
    const float* __restrict__ fx, const float* __restrict__ fy,
    const float* __restrict__ x, const float* __restrict__ y,
    const float* __restrict__ wbuf,
    float* __restrict__ part3, float* __restrict__ dout)
{
    const int blk = blockIdx.x;
    const int jh = blk & 1;
    const int b = (blk >> 1) & (NB-1);
    const int side = (blk >> 1) >> 6;
    const float* feat = side ? fy : fx;
    const float* targ = side ? x : y;
    const float* bmat = side ? y : x;
    const float* wb = wbuf + (size_t)(b*2+side)*WSTRIDE;
    const int t = threadIdx.x;
    const int lane = t & 63, wv = t >> 6;          // wv 0..15
    const int lrow = lane & 15, lkb = (lane>>4)*16;

    __shared__ unsigned short resA[256*72];
    __shared__ unsigned short tgB [256*72];
    __shared__ unsigned short Zh[2*4608], Zl[2*4608];
    __shared__ unsigned short Wth[4608], Wtl[4608];
    __shared__ float c0s[64];
    __shared__ float nAs[256], nBs[256];
    __shared__ float red[16][3];
    __shared__ float lred[16];

    {
        int k = t>>4, c0 = (t&15)*4;         // 1024 float4 over W rows k
        float4 v = *(const float4*)(wb + (size_t)k*64 + c0);
        sw2(Wth, Wtl, (c0+0)*72 + k, v.x);
        sw2(Wth, Wtl, (c0+1)*72 + k, v.y);
        sw2(Wth, Wtl, (c0+2)*72 + k, v.z);
        sw2(Wth, Wtl, (c0+3)*72 + k, v.w);
    }
    if (t<64) c0s[t] = wb[4096+t];
    const float zinv = wb[4160], tinv = wb[4161];
    #pragma unroll
    for (int u=0;u<4;u++){
        int id = t + 1024*u;                 // 4096 float4
        int r = id>>4, c0 = (id&15)*4;
        float4 v = *(const float4*)(bmat + ((size_t)(b*NS+r))*ND + c0);
        ushort4 h;
        h.x=f2bf(v.x); h.y=f2bf(v.y); h.z=f2bf(v.z); h.w=f2bf(v.w);
        *(ushort4*)(tgB + r*72 + c0) = h;
    }
    {
        int r = t>>4, c0 = (t&15)*4;         // 1024 float4, chunk 0
        float4 v = *(const float4*)(feat + ((size_t)(b*NS + r))*NH2 + c0);
        sw2x2(Zh, Zl, r*72+c0,   v.x, v.y);
        sw2x2(Zh, Zl, r*72+c0+2, v.z, v.w);
    }
    __syncthreads();

    // ---- residual: 4 chunks of 64 rows; wave w -> (rt=w&3, ct=w>>2), 1 tile each ----
    const int rt = wv & 3, ct = wv >> 2;     // ct 0..3
    float lacc = 0.f;
    for (int c=0; c<4; c++){
        if (c < 3){
            unsigned short* zh = Zh + ((c+1)&1)*4608;
            unsigned short* zl = Zl + ((c+1)&1)*4608;
            int r = t>>4, c0 = (t&15)*4;
            float4 v = *(const float4*)(feat + ((size_t)(b*NS + (c+1)*64 + r))*NH2 + c0);
            sw2x2(zh, zl, r*72+c0,   v.x, v.y);
            sw2x2(zh, zl, r*72+c0+2, v.z, v.w);
        }
        const unsigned short* zh = Zh + (c&1)*4608;
        const unsigned short* zl = Zl + (c&1)*4608;
        f32x4 zz = {0.f,0.f,0.f,0.f};
        f32x4 acc = mm64(zh, zl, Wth, Wtl, 16*rt, 16*ct, lrow, lkb, zz);
        const int r0 = 16*rt + (lane>>4)*4;
        const int gj = 16*ct + lrow;
        const float cc = c0s[gj];
        #pragma unroll
        for (int e=0;e<4;e++){
            const int grow = c*64 + r0 + e;
            float qv = targ[((size_t)(b*NS+grow))*ND + gj];
            float rr = tinv*qv - zinv*acc[e] - cc;
            lacc += rr*rr;
            resA[grow*72 + gj] = f2bf(rr);
        }
        __syncthreads();
    }

    {
        float l = lacc;
        #pragma unroll
        for (int off=32; off; off>>=1) l += __shfl_down(l, off);
        if (lane==0) lred[wv] = l;
    }
    if (t < 256){
        float sa=0.f, sb=0.f;
        #pragma unroll
        for (int j8=0;j8<8;j8++){
            bf16x8 va = *(const bf16x8*)((const char*)resA + (size_t)t*144 + j8*16);
            bf16x8 vb = *(const bf16x8*)((const char*)tgB  + (size_t)t*144 + j8*16);
            #pragma unroll
            for (int e2=0;e2<8;e2++){
                float fa = bf2f((unsigned short)va[e2]);
                float fb = bf2f((unsigned short)vb[e2]);
                sa += fa*fa; sb += fb*fb;
            }
        }
        nAs[t] = sa; nBs[t] = sb;
    }
    __syncthreads();
    if (t==0 && jh==0){
        float ls = 0.f;
        #pragma unroll
        for (int w=0;w<16;w++) ls += lred[w];
        dout[(side?256:192)+b] = ls;
    }

    // ---- Gram + exp: wave w -> i-tile i0 = 16w ----
    const char* pA = (const char*)resA;
    const char* pB = (const char*)tgB;
    const f32x4 zero4 = {0.f, 0.f, 0.f, 0.f};
    const float CEXP = -2.8853900817779268f;

    float Sa=0.f, Sb=0.f, Sab=0.f;
    {
        const int i0 = wv*16;
        const int arow = i0 + lrow;
        bf16x8 aA0 = *(const bf16x8*)(pA + arow*144 + lkb);
        bf16x8 aA1 = *(const bf16x8*)(pA + arow*144 + lkb + 64);
        bf16x8 aB0 = *(const bf16x8*)(pB + arow*144 + lkb);
        bf16x8 aB1 = *(const bf16x8*)(pB + arow*144 + lkb + 64);
        float nAi[4], nBi[4];
        #pragma unroll
        for (int e=0;e<4;e++){
            int gi = i0 + (lane>>4)*4 + e;
            nAi[e] = nAs[gi]; nBi[e] = nBs[gi];
        }
        #pragma unroll
        for (int jt=0; jt<8; jt++){
            const int j0 = jh*128 + jt*16;
            const int brow = j0 + lrow;
            bf16x8 bA0 = *(const bf16x8*)(pA + brow*144 + lkb);
            bf16x8 bA1 = *(const bf16x8*)(pA + brow*144 + lkb + 64);
            bf16x8 bB0 = *(const bf16x8*)(pB + brow*144 + lkb);
            bf16x8 bB1 = *(const bf16x8*)(pB + brow*144 + lkb + 64);
            f32x4 cA = __builtin_amdgcn_mfma_f32_16x16x32_bf16(aA0, bA0, zero4, 0, 0, 0);
            cA = __builtin_amdgcn_mfma_f32_16x16x32_bf16(aA1, bA1, cA, 0, 0, 0);
            f32x4 cB = __builtin_amdgcn_mfma_f32_16x16x32_bf16(aB0, bB0, zero4, 0, 0, 0);
            cB = __builtin_amdgcn_mfma_f32_16x16x32_bf16(aB1, bB1, cB, 0, 0, 0);
            const int gj = j0 + lrow;
            const float nAj = nAs[gj], nBj = nBs[gj];
            #pragma unroll
            for (int e=0;e<4;e++){
                const int gi = i0 + (lane>>4)*4 + e;
                const float dda = (gi==gj) ? 0.f : (nAi[e] + nAj - 2.f*cA[e]);
                const float ddb = (gi==gj) ? 0.f : (nBi[e] + nBj - 2.f*cB[e]);
                const float ka2 = exp2f(CEXP*dda);
                const float kb2 = exp2f(CEXP*ddb);
                Sa += ka2; Sb += kb2; Sab += ka2*kb2;
            }
        }
    }
    #pragma unroll
    for (int off=32; off; off>>=1){
        Sa += __shfl_down(Sa,off); Sb += __shfl_down(Sb,off); Sab += __shfl_down(Sab,off);
    }
    if (lane==0){ red[wv][0]=Sa; red[wv][1]=Sb; red[wv][2]=Sab; }
    __syncthreads();
    if (t==0){
        float s0=0.f, s1=0.f, s2=0.f;
        #pragma unroll
        for (int w=0;w<16;w++){ s0 += red[w][0]; s1 += red[w][1]; s2 += red[w][2]; }
        float* o = part3 + (size_t)blk*3;
        o[0] = s0; o[1] = s1; o[2] = s2;
    }
}

// =================== K4 ===================
__global__ __launch_bounds__(64) void k4_final(
    const float* __restrict__ mean_part, const float* __restrict__ part3,
    const float* __restrict__ wc1, const float* __restrict__ bc1,
    const float* __restrict__ bn_gamma, const float* __restrict__ bn_beta,
    const float* __restrict__ w2, const float* __restrict__ b2,
    const float* __restrict__ wc2, const float* __restrict__ bc2,
    float* __restrict__ dout)
{
    const int t = threadIdx.x;
    __shared__ float ic[64][5];
    __shared__ float mu[5], iv[5];

    float o0 = bc1[0], o1 = bc1[1], o2 = bc1[2];
    for (int c=0;c<64;c++){
        float mv = mean_part[(t*4+0)*64+c] + mean_part[(t*4+1)*64+c]
                 + mean_part[(t*4+2)*64+c] + mean_part[(t*4+3)*64+c];
        mv *= (1.0f/256.0f);
        o0 += mv*wc1[c*3+0]; o1 += mv*wc1[c*3+1]; o2 += mv*wc1[c*3+2];
    }
    dout[t*3+0]=o0; dout[t*3+1]=o1; dout[t*3+2]=o2;
    {
        float m = fmaxf(o0,fmaxf(o1,o2));
        float e0=__expf(o0-m), e1=__expf(o1-m), e2=__expf(o2-m);
        float inv = 1.f/(e0+e1+e2);
        dout[640+t*3+0]=e0*inv; dout[640+t*3+1]=e1*inv; dout[640+t*3+2]=e2*inv;
    }
    float exy[2];
    #pragma unroll
    for (int side=0; side<2; side++){
        const float* pp = part3 + (size_t)((side*NB + t)*2)*3;
        float Sa = pp[0]+pp[3];
        float Sb = pp[1]+pp[4];
        float Sab= pp[2]+pp[5];
        float Hx  = 16.f - log2f(Sa);
        float Hy  = 16.f - log2f(Sb);
        float Hxy = 16.f - log2f(Sab);
        float mi = (Hx + Hy - Hxy) / fmaxf(Hx, Hy);
        dout[(side?384:320)+t] = mi;
        exy[side] = mi;
    }
    ic[t][0]=o0; ic[t][1]=o1; ic[t][2]=o2; ic[t][3]=exy[0]; ic[t][4]=exy[1];
    __syncthreads();
    if (t<5){
        float m=0.f;
        for (int bb=0;bb<64;bb++) m += ic[bb][t];
        m *= (1.f/64.f);
        float v=0.f;
        for (int bb=0;bb<64;bb++){ float d=ic[bb][t]-m; v+=d*d; }
        v *= (1.f/64.f);
        mu[t]=m; iv[t]=1.f/sqrtf(v+1e-5f);
    }
    __syncthreads();
    float vn[5];
    #pragma unroll
    for (int c=0;c<5;c++) vn[c] = (ic[t][c]-mu[c])*iv[c]*bn_gamma[c]+bn_beta[c];
    float q0=bc2[0], q1=bc2[1], q2=bc2[2];
    for (int j=0;j<64;j++){
        float hh = b2[j];
        #pragma unroll
        for (int c=0;c<5;c++) hh += vn[c]*w2[c*64+j];
        hh = fmaxf(hh,0.f);
        q0 += hh*wc2[j*3+0]; q1 += hh*wc2[j*3+1]; q2 += hh*wc2[j*3+2];
    }
    dout[448+t*3+0]=q0; dout[448+t*3+1]=q1; dout[448+t*3+2]=q2;
    float m = fmaxf(q0,fmaxf(q1,q2));
    float e0=__expf(q0-m), e1=__expf(q1-m), e2=__expf(q2-m);
    float inv=1.f/(e0+e1+e2);
    dout[832+t*3+0]=e0*inv; dout[832+t*3+1]=e1*inv; dout[832+t*3+2]=e2*inv;
}

extern "C" void kernel_launch(void* const* d_in, const int* in_sizes, int n_in,
                              void* d_out, int out_size, void* d_ws, size_t ws_size,
                              hipStream_t stream)
{
    const float* x     = (const float*)d_in[0];
    const float* y     = (const float*)d_in[1];
    const float* w11_1 = (const float*)d_in[2];
    const float* b11_1 = (const float*)d_in[3];
    const float* w11_2 = (const float*)d_in[4];
    const float* b11_2 = (const float*)d_in[5];
    const float* w12_1 = (const float*)d_in[6];
    const float* b12_1 = (const float*)d_in[7];
    const float* w12_2 = (const float*)d_in[8];
    const float* b12_2 = (const float*)d_in[9];
    const float* wc1   = (const float*)d_in[10];
    const float* bc1   = (const float*)d_in[11];
    const float* bn_g  = (const float*)d_in[12];
    const float* bn_b  = (const float*)d_in[13];
    const float* w2    = (const float*)d_in[14];
    const float* b2    = (const float*)d_in[15];
    const float* wc2   = (const float*)d_in[16];
    const float* bc2   = (const float*)d_in[17];

    float* ws   = (float*)d_ws;
    float* dout = (float*)d_out;
    float* out_x = ws;                           // 1,048,576 floats
    float* out_y = ws + 1048576;
    float* mean_part = ws + 2097152;             // 16384
    float* part3 = mean_part + 16384;            // 768 (alloc 3840)
    float* wbuf  = part3 + 3840;                 // 128*4224 = 540672

    hipLaunchKernelGGL(k1_fused, dim3(NB*4), dim3(1024), 0, stream,
        x,y,w11_1,b11_1,w11_2,b11_2,w12_1,b12_1,w12_2,b12_2,
        out_x,out_y,mean_part);
    hipLaunchKernelGGL(k2ab, dim3(2*NB), dim3(512), 0, stream,
        out_x,out_y,x,y,wbuf);
    hipLaunchKernelGGL(kRG, dim3(NB*2*2), dim3(1024), 0, stream,
        out_x,out_y,x,y,wbuf,part3,dout);
    hipLaunchKernelGGL(k4_final, dim3(1), dim3(64), 0, stream,
        mean_part,part3,wc1,bc1,bn_g,bn_b,w2,b2,wc2,bc2,dout);
}